// Round 9
// baseline (464.933 us; speedup 1.0000x reference)
//
#include <hip/hip_runtime.h>
#include <cstddef>

#define BB 8
#define NN 1024
#define KK 20
#define CCAT 169
#define NT 16  // n-tiles of 64 in final fused GEMM

// ---------------- neg dist, symmetric triangle tiles, norms fused in --------
// dist[b][n][m] = 2*sum_f x[f][n]*x[f][m] - ||x_n||^2 - ||x_m||^2  (symmetric)
__global__ __launch_bounds__(256) void dist_tile_kernel(
    const float* __restrict__ src, int bs, int F, float* __restrict__ dist) {
  __shared__ float As[8][128];
  __shared__ float Bs[8][128];
  int b = blockIdx.z;
  int rem = blockIdx.x, bi = 0;
  while (rem >= 8 - bi) { rem -= 8 - bi; ++bi; }
  int bj = bi + rem;
  int n0 = bi * 128;
  int m0 = bj * 128;
  int t = threadIdx.x;
  int tx = t & 15, ty = t >> 4;
  const float* p = src + (size_t)b * bs;

  float acc[8][8];
  float xn[8], xm[8];
#pragma unroll
  for (int i = 0; i < 8; ++i) {
    xn[i] = 0.f;
    xm[i] = 0.f;
#pragma unroll
    for (int j = 0; j < 8; ++j) acc[i][j] = 0.f;
  }

  int fr = t >> 5;
  int cc = (t & 31) << 2;
  for (int f0 = 0; f0 < F; f0 += 8) {
    int f = f0 + fr;
    float4 av = {0.f, 0.f, 0.f, 0.f}, bv = {0.f, 0.f, 0.f, 0.f};
    if (f < F) {
      av = *(const float4*)(p + (size_t)f * NN + n0 + cc);
      bv = *(const float4*)(p + (size_t)f * NN + m0 + cc);
    }
    __syncthreads();
    *(float4*)&As[fr][cc] = av;
    *(float4*)&Bs[fr][cc] = bv;
    __syncthreads();
#pragma unroll
    for (int f2 = 0; f2 < 8; ++f2) {
      float4 al = *(const float4*)&As[f2][ty << 2];
      float4 ah = *(const float4*)&As[f2][64 + (ty << 2)];
      float4 bl = *(const float4*)&Bs[f2][tx << 2];
      float4 bh = *(const float4*)&Bs[f2][64 + (tx << 2)];
      float a[8] = {al.x, al.y, al.z, al.w, ah.x, ah.y, ah.z, ah.w};
      float bb[8] = {bl.x, bl.y, bl.z, bl.w, bh.x, bh.y, bh.z, bh.w};
#pragma unroll
      for (int i = 0; i < 8; ++i) xn[i] += a[i] * a[i];
#pragma unroll
      for (int j = 0; j < 8; ++j) xm[j] += bb[j] * bb[j];
#pragma unroll
      for (int i = 0; i < 8; ++i)
#pragma unroll
        for (int j = 0; j < 8; ++j) acc[i][j] += a[i] * bb[j];
    }
  }

#pragma unroll
  for (int i = 0; i < 8; ++i)
#pragma unroll
    for (int j = 0; j < 8; ++j) acc[i][j] = 2.f * acc[i][j] - xn[i] - xm[j];

#pragma unroll
  for (int i = 0; i < 8; ++i) {
    int n = n0 + ((i < 4) ? ((ty << 2) + i) : (64 + (ty << 2) + i - 4));
    float* dr = dist + (((size_t)b * NN + n) << 10);
    *(float4*)(dr + m0 + (tx << 2)) =
        make_float4(acc[i][0], acc[i][1], acc[i][2], acc[i][3]);
    *(float4*)(dr + m0 + 64 + (tx << 2)) =
        make_float4(acc[i][4], acc[i][5], acc[i][6], acc[i][7]);
  }

  if (bi != bj) {
#pragma unroll
    for (int j = 0; j < 8; ++j) {
      int m = m0 + ((j < 4) ? ((tx << 2) + j) : (64 + (tx << 2) + j - 4));
      float* dr = dist + (((size_t)b * NN + m) << 10);
      *(float4*)(dr + n0 + (ty << 2)) =
          make_float4(acc[0][j], acc[1][j], acc[2][j], acc[3][j]);
      *(float4*)(dr + n0 + 64 + (ty << 2)) =
          make_float4(acc[4][j], acc[5][j], acc[6][j], acc[7][j]);
    }
  }
}

// ---------------- top-k (k=20) per row, one wave per row ----------------
__device__ __forceinline__ unsigned long long shfl_xor_u64(
    unsigned long long v, int off) {
  unsigned lo = (unsigned)v, hi = (unsigned)(v >> 32);
  lo = __shfl_xor(lo, off, 64);
  hi = __shfl_xor(hi, off, 64);
  return ((unsigned long long)hi << 32) | lo;
}

__global__ __launch_bounds__(256) void topk_kernel(
    const float* __restrict__ dist, int* __restrict__ idx_out) {
  int wave = threadIdx.x >> 6;
  int lane = threadIdx.x & 63;
  int row = blockIdx.x * 4 + wave;
  const float* d = dist + ((size_t)row << 10);

  unsigned long long key[16];
#pragma unroll
  for (int s = 0; s < 16; ++s) {
    int m = lane + (s << 6);
    unsigned u = __float_as_uint(d[m]);
    u = (u & 0x80000000u) ? ~u : (u | 0x80000000u);
    key[s] = ((unsigned long long)u << 32) | (unsigned)(NN - 1 - m);
  }

#pragma unroll
  for (int size = 2; size <= 16; size <<= 1) {
#pragma unroll
    for (int stride = size >> 1; stride > 0; stride >>= 1) {
#pragma unroll
      for (int i = 0; i < 16; ++i) {
        int j = i ^ stride;
        if (j > i) {
          unsigned long long a = key[i], c = key[j];
          bool desc = ((i & size) == 0);
          bool sw = desc ? (a < c) : (a > c);
          key[i] = sw ? c : a;
          key[j] = sw ? a : c;
        }
      }
    }
  }

  int* out = idx_out + row * KK;
  unsigned long long head = key[0];
  for (int r = 0; r < KK; ++r) {
    unsigned long long w = head;
#pragma unroll
    for (int off = 32; off > 0; off >>= 1) {
      unsigned long long o = shfl_xor_u64(w, off);
      if (o > w) w = o;
    }
    if (lane == 0) out[r] = (NN - 1) - (int)(w & 0xFFFFFFFFull);
    if (head == w) {
#pragma unroll
      for (int s = 0; s < 15; ++s) key[s] = key[s + 1];
      key[15] = 0ull;
      head = key[0];
    }
  }
}

// ---------------- fused transform + edge combine + mean over k --------------
// R8 version: 256 threads, n-split grid.y, phase A templated on D.
template <int DD>
__global__ __launch_bounds__(256) void edge_fused_kernel(
    const float* __restrict__ src, int bs, int Co, int nsplit,
    const float* __restrict__ Wf, const float* __restrict__ Wd,
    const int* __restrict__ idx, int ooff, float* __restrict__ xcat) {
  __shared__ float2 Ulds[3 * NN];  // 24 KB {Uf,Ud}
  __shared__ float2 Vlds[3 * NN];  // 24 KB {Vf,Vd}
  __shared__ float4 Wlds[48];      // {wfa, wfb, wda, wdb} per i, DD<=42
  int bo = blockIdx.x;
  int b = bo / Co, o = bo % Co;
  int t = threadIdx.x;

  if (t < DD) {
    float wfa = Wf[o * 2 * DD + t];
    float wfb = Wf[o * 2 * DD + DD + t] - wfa;
    float wda = Wd[o * 2 * DD + t];
    float wdb = Wd[o * 2 * DD + DD + t] - wda;
    Wlds[t] = make_float4(wfa, wfb, wda, wdb);
  }
  __syncthreads();

  const float* sb = src + (size_t)b * bs;
  {
    int c0 = t << 2;
    float4 uf[3], vf[3], ud[3], vd[3];
#pragma unroll
    for (int r = 0; r < 3; ++r) {
      uf[r] = make_float4(0.f, 0.f, 0.f, 0.f);
      vf[r] = make_float4(0.f, 0.f, 0.f, 0.f);
      ud[r] = make_float4(0.f, 0.f, 0.f, 0.f);
      vd[r] = make_float4(0.f, 0.f, 0.f, 0.f);
    }
#pragma unroll 2
    for (int i = 0; i < DD; ++i) {
      const float* row = sb + (size_t)i * 3 * NN + c0;
      float4 s[3];
      s[0] = *(const float4*)(row);
      s[1] = *(const float4*)(row + 1024);
      s[2] = *(const float4*)(row + 2048);
      float4 w = Wlds[i];
#pragma unroll
      for (int r = 0; r < 3; ++r) {
        uf[r].x += w.x * s[r].x; uf[r].y += w.x * s[r].y;
        uf[r].z += w.x * s[r].z; uf[r].w += w.x * s[r].w;
        vf[r].x += w.y * s[r].x; vf[r].y += w.y * s[r].y;
        vf[r].z += w.y * s[r].z; vf[r].w += w.y * s[r].w;
        ud[r].x += w.z * s[r].x; ud[r].y += w.z * s[r].y;
        ud[r].z += w.z * s[r].z; ud[r].w += w.z * s[r].w;
        vd[r].x += w.w * s[r].x; vd[r].y += w.w * s[r].y;
        vd[r].z += w.w * s[r].z; vd[r].w += w.w * s[r].w;
      }
    }
#pragma unroll
    for (int r = 0; r < 3; ++r) {
      int g = t + 256 * r;
      *(float4*)&Ulds[(g << 2) + 0] =
          make_float4(uf[r].x, ud[r].x, uf[r].y, ud[r].y);
      *(float4*)&Ulds[(g << 2) + 2] =
          make_float4(uf[r].z, ud[r].z, uf[r].w, ud[r].w);
      *(float4*)&Vlds[(g << 2) + 0] =
          make_float4(vf[r].x, vd[r].x, vf[r].y, vd[r].y);
      *(float4*)&Vlds[(g << 2) + 2] =
          make_float4(vf[r].z, vd[r].z, vf[r].w, vd[r].w);
    }
  }
  __syncthreads();

  const float inv_k = 1.f / KK;
  int cnt = NN / nsplit;
  int nbase = blockIdx.y * cnt;
  for (int n = nbase + t; n < nbase + cnt; n += 256) {
    float2 v0 = Vlds[n];
    float2 v1 = Vlds[NN + n];
    float2 v2 = Vlds[2 * NN + n];
    const int4* ip = (const int4*)(idx + (b * NN + n) * KK);
    float a0 = 0.f, a1 = 0.f, a2 = 0.f;
#pragma unroll
    for (int q = 0; q < 5; ++q) {
      int4 iv = ip[q];
      int nbs[4] = {iv.x, iv.y, iv.z, iv.w};
#pragma unroll
      for (int jj = 0; jj < 4; ++jj) {
        int nb = nbs[jj];
        float2 u0 = Ulds[nb];
        float2 u1 = Ulds[NN + nb];
        float2 u2 = Ulds[2 * NN + nb];
        float pf0 = u0.x + v0.x, pd0 = u0.y + v0.y;
        float pf1 = u1.x + v1.x, pd1 = u1.y + v1.y;
        float pf2 = u2.x + v2.x, pd2 = u2.y + v2.y;
        float dot = pf0 * pd0 + pf1 * pd1 + pf2 * pd2;
        float dsq = pd0 * pd0 + pd1 * pd1 + pd2 * pd2;
        float g = (dot >= 0.f) ? 0.f : 0.8f * dot / (dsq + 1e-6f);
        a0 += pf0 - g * pd0;
        a1 += pf1 - g * pd1;
        a2 += pf2 - g * pd2;
      }
    }
    size_t ob = (size_t)b * CCAT * 3 * NN + (size_t)(ooff + o) * 3 * NN + n;
    xcat[ob] = a0 * inv_k;
    xcat[ob + NN] = a1 * inv_k;
    xcat[ob + 2 * NN] = a2 * inv_k;
  }
}

// ---------------- dvec: dv[b][c][n] = sum_f Wd4[f] * xcat[b][f][c][n] -------
// Wd4 is (1,169): dv is o-independent, so hoist it out of final_fused where
// all 6 o-blocks recomputed it. Single f-ascending fma chain = same order.
__global__ __launch_bounds__(256) void dvec_kernel(
    const float* __restrict__ xcat, const float* __restrict__ Wd4,
    float* __restrict__ dvg) {
  int t = blockIdx.x * 256 + threadIdx.x;  // < BB*3*NN
  int b = t >> 11;  // t / 3072 requires div; 3072 = 3*1024 not pow2
  b = t / 3072;
  int r = t - b * 3072;
  const float* xp = xcat + (size_t)b * CCAT * 3 * NN + r;
  float s = 0.f;
  for (int f = 0; f < CCAT; ++f) s += Wd4[f] * xp[(size_t)f * 3 * NN];
  dvg[t] = s;
}

// ---------------- fused final GEMM + VN-leakyrelu + partial n-sum ----------
// Software-pipelined double-buffer: one barrier per tile; stage(t+1) issued
// before compute(t); vmcnt wait lands at the post-compute store. #pragma
// unroll 1 keeps live ranges per-tile (R1's unrolled dbuf hit 236 VGPR).
// dv removed (precomputed by dvec_kernel).
__global__ __launch_bounds__(256) void final_fused_kernel(
    const float* __restrict__ xcat, const float* __restrict__ Wf4,
    const float* __restrict__ dvg, float* __restrict__ part) {
  __shared__ float Ws[2][16][64];
  __shared__ float Xs[2][3][16][64];
  int b = blockIdx.z;
  int o0 = blockIdx.y * 64;
  int n0 = blockIdx.x * 64;
  int t = threadIdx.x;
  int tx = t & 15, ty = t >> 4;

  float acc[3][4][4];  // [c][o_i][n_j]
#pragma unroll
  for (int c = 0; c < 3; ++c)
#pragma unroll
    for (int i = 0; i < 4; ++i)
#pragma unroll
      for (int j = 0; j < 4; ++j) acc[c][i][j] = 0.f;

  const float* xb = xcat + (size_t)b * CCAT * 3 * NN;
  const int NTILE = (CCAT + 15) / 16;  // 11

  float4 xv[3];
  float wv[4];
  // prologue: stage tile 0
  {
    int f = ty;
#pragma unroll
    for (int c = 0; c < 3; ++c)
      xv[c] = *(const float4*)(xb + ((size_t)f * 3 + c) * NN + n0 + (tx << 2));
#pragma unroll
    for (int q = 0; q < 4; ++q) {
      int o = o0 + (tx << 2) + q;
      wv[q] = (o < 341) ? Wf4[(size_t)o * CCAT + f] : 0.f;
    }
#pragma unroll
    for (int c = 0; c < 3; ++c) *(float4*)&Xs[0][c][ty][tx << 2] = xv[c];
    *(float4*)&Ws[0][ty][tx << 2] = make_float4(wv[0], wv[1], wv[2], wv[3]);
  }

#pragma unroll 1
  for (int tt = 0; tt < NTILE; ++tt) {
    int buf = tt & 1;
    __syncthreads();  // tile tt stores visible; buf^1 free (all past tt-1)
    if (tt + 1 < NTILE) {
      int f = (tt + 1) * 16 + ty;
#pragma unroll
      for (int c = 0; c < 3; ++c) {
        xv[c] = make_float4(0.f, 0.f, 0.f, 0.f);
        if (f < CCAT)
          xv[c] =
              *(const float4*)(xb + ((size_t)f * 3 + c) * NN + n0 + (tx << 2));
      }
#pragma unroll
      for (int q = 0; q < 4; ++q) {
        int o = o0 + (tx << 2) + q;
        wv[q] = (o < 341 && f < CCAT) ? Wf4[(size_t)o * CCAT + f] : 0.f;
      }
    }
#pragma unroll
    for (int f2 = 0; f2 < 16; ++f2) {
      float4 w = *(const float4*)&Ws[buf][f2][ty << 2];
      float wa[4] = {w.x, w.y, w.z, w.w};
#pragma unroll
      for (int c = 0; c < 3; ++c) {
        float4 x = *(const float4*)&Xs[buf][c][f2][tx << 2];
        float xa[4] = {x.x, x.y, x.z, x.w};
#pragma unroll
        for (int i = 0; i < 4; ++i)
#pragma unroll
          for (int j = 0; j < 4; ++j) acc[c][i][j] += wa[i] * xa[j];
      }
    }
    if (tt + 1 < NTILE) {
#pragma unroll
      for (int c = 0; c < 3; ++c) *(float4*)&Xs[buf ^ 1][c][ty][tx << 2] = xv[c];
      *(float4*)&Ws[buf ^ 1][ty][tx << 2] =
          make_float4(wv[0], wv[1], wv[2], wv[3]);
    }
  }

  float dvv[3][4];
#pragma unroll
  for (int c = 0; c < 3; ++c) {
    float4 dq = *(const float4*)(dvg + (size_t)b * 3 * NN + c * NN + n0 +
                                 (tx << 2));
    dvv[c][0] = dq.x; dvv[c][1] = dq.y; dvv[c][2] = dq.z; dvv[c][3] = dq.w;
  }

  float s[3][4];
#pragma unroll
  for (int c = 0; c < 3; ++c)
#pragma unroll
    for (int i = 0; i < 4; ++i) s[c][i] = 0.f;
#pragma unroll
  for (int i = 0; i < 4; ++i) {
#pragma unroll
    for (int j = 0; j < 4; ++j) {
      float d0 = dvv[0][j], d1 = dvv[1][j], d2 = dvv[2][j];
      float p0 = acc[0][i][j], p1 = acc[1][i][j], p2 = acc[2][i][j];
      float dot = p0 * d0 + p1 * d1 + p2 * d2;
      float dsq = d0 * d0 + d1 * d1 + d2 * d2;
      float g = (dot >= 0.f) ? 0.f : 0.8f * dot / (dsq + 1e-6f);
      s[0][i] += p0 - g * d0;
      s[1][i] += p1 - g * d1;
      s[2][i] += p2 - g * d2;
    }
  }

#pragma unroll
  for (int off = 1; off < 16; off <<= 1) {
#pragma unroll
    for (int c = 0; c < 3; ++c)
#pragma unroll
      for (int i = 0; i < 4; ++i) s[c][i] += __shfl_xor(s[c][i], off, 64);
  }
  if (tx == 0) {
#pragma unroll
    for (int i = 0; i < 4; ++i) {
      int o = o0 + (ty << 2) + i;
      if (o < 341) {
#pragma unroll
        for (int c = 0; c < 3; ++c)
          part[(((size_t)b * 341 + o) * 3 + c) * NT + blockIdx.x] = s[c][i];
      }
    }
  }
}

__global__ void final_reduce_kernel(const float* __restrict__ part,
                                    float* __restrict__ out) {
  int t = blockIdx.x * 256 + threadIdx.x;
  if (t >= BB * 341 * 3) return;
  const float* p = part + (size_t)t * NT;
  float s = 0.f;
#pragma unroll
  for (int nt = 0; nt < NT; ++nt) s += p[nt];
  out[t] = s * (1.f / 1024.f);
}

extern "C" void kernel_launch(void* const* d_in, const int* in_sizes, int n_in,
                              void* d_out, int out_size, void* d_ws,
                              size_t ws_size, hipStream_t stream) {
  (void)in_sizes; (void)n_in; (void)out_size; (void)ws_size;
  const float* x = (const float*)d_in[0];
  const float* Wf[5] = {(const float*)d_in[1], (const float*)d_in[3],
                        (const float*)d_in[5], (const float*)d_in[7],
                        (const float*)d_in[9]};
  const float* Wd[5] = {(const float*)d_in[2], (const float*)d_in[4],
                        (const float*)d_in[6], (const float*)d_in[8],
                        (const float*)d_in[10]};

  float* ws = (float*)d_ws;
  float* dist = ws;
  float* part = ws;               // dist region dead once final phase runs
  float* dvg = ws + (1 << 22);    // 24576 floats at +4M, clear of part (131K)
  size_t off = (size_t)BB * NN * NN;
  int* idx = (int*)(ws + off);
  off += (size_t)BB * NN * KK;
  float* xcat = ws + off;

  struct LayerCfg { int D, Co, inoff, ooff, nsplit; };
  const LayerCfg L[4] = {
      {1, 21, 0, 0, 4},
      {21, 21, 0, 21, 4},
      {21, 42, 21, 42, 2},
      {42, 85, 42, 84, 1},
  };

  for (int l = 0; l < 4; ++l) {
    const float* src = (l == 0) ? x : (xcat + (size_t)L[l].inoff * 3 * NN);
    int bs = (l == 0) ? 3 * NN : CCAT * 3 * NN;
    int D = L[l].D, Co = L[l].Co;

    dist_tile_kernel<<<dim3(36, 1, BB), 256, 0, stream>>>(src, bs, 3 * D, dist);
    topk_kernel<<<(BB * NN) / 4, 256, 0, stream>>>(dist, idx);
    dim3 eg(BB * Co, L[l].nsplit);
    if (D == 1)
      edge_fused_kernel<1><<<eg, 256, 0, stream>>>(
          src, bs, Co, L[l].nsplit, Wf[l], Wd[l], idx, L[l].ooff, xcat);
    else if (D == 21)
      edge_fused_kernel<21><<<eg, 256, 0, stream>>>(
          src, bs, Co, L[l].nsplit, Wf[l], Wd[l], idx, L[l].ooff, xcat);
    else
      edge_fused_kernel<42><<<eg, 256, 0, stream>>>(
          src, bs, Co, L[l].nsplit, Wf[l], Wd[l], idx, L[l].ooff, xcat);
  }

  dvec_kernel<<<(BB * 3 * NN) / 256, 256, 0, stream>>>(xcat, Wd[4], dvg);
  final_fused_kernel<<<dim3(NT, 6, BB), 256, 0, stream>>>(xcat, Wf[4], dvg,
                                                          part);
  final_reduce_kernel<<<(BB * 341 * 3 + 255) / 256, 256, 0, stream>>>(
      part, (float*)d_out);
}

// Round 10
// 426.999 us; speedup vs baseline: 1.0888x; 1.0888x over previous
//
#include <hip/hip_runtime.h>
#include <cstddef>

#define BB 8
#define NN 1024
#define KK 20
#define CCAT 169
#define NT 16   // n-tiles of 64 in final fused GEMM
#define WTLD 384  // padded row length of transposed Wf4

// ---------------- neg dist, symmetric triangle tiles, norms fused in --------
// dist[b][n][m] = 2*sum_f x[f][n]*x[f][m] - ||x_n||^2 - ||x_m||^2  (symmetric)
__global__ __launch_bounds__(256) void dist_tile_kernel(
    const float* __restrict__ src, int bs, int F, float* __restrict__ dist) {
  __shared__ float As[8][128];
  __shared__ float Bs[8][128];
  int b = blockIdx.z;
  int rem = blockIdx.x, bi = 0;
  while (rem >= 8 - bi) { rem -= 8 - bi; ++bi; }
  int bj = bi + rem;
  int n0 = bi * 128;
  int m0 = bj * 128;
  int t = threadIdx.x;
  int tx = t & 15, ty = t >> 4;
  const float* p = src + (size_t)b * bs;

  float acc[8][8];
  float xn[8], xm[8];
#pragma unroll
  for (int i = 0; i < 8; ++i) {
    xn[i] = 0.f;
    xm[i] = 0.f;
#pragma unroll
    for (int j = 0; j < 8; ++j) acc[i][j] = 0.f;
  }

  int fr = t >> 5;
  int cc = (t & 31) << 2;
  for (int f0 = 0; f0 < F; f0 += 8) {
    int f = f0 + fr;
    float4 av = {0.f, 0.f, 0.f, 0.f}, bv = {0.f, 0.f, 0.f, 0.f};
    if (f < F) {
      av = *(const float4*)(p + (size_t)f * NN + n0 + cc);
      bv = *(const float4*)(p + (size_t)f * NN + m0 + cc);
    }
    __syncthreads();
    *(float4*)&As[fr][cc] = av;
    *(float4*)&Bs[fr][cc] = bv;
    __syncthreads();
#pragma unroll
    for (int f2 = 0; f2 < 8; ++f2) {
      float4 al = *(const float4*)&As[f2][ty << 2];
      float4 ah = *(const float4*)&As[f2][64 + (ty << 2)];
      float4 bl = *(const float4*)&Bs[f2][tx << 2];
      float4 bh = *(const float4*)&Bs[f2][64 + (tx << 2)];
      float a[8] = {al.x, al.y, al.z, al.w, ah.x, ah.y, ah.z, ah.w};
      float bb[8] = {bl.x, bl.y, bl.z, bl.w, bh.x, bh.y, bh.z, bh.w};
#pragma unroll
      for (int i = 0; i < 8; ++i) xn[i] += a[i] * a[i];
#pragma unroll
      for (int j = 0; j < 8; ++j) xm[j] += bb[j] * bb[j];
#pragma unroll
      for (int i = 0; i < 8; ++i)
#pragma unroll
        for (int j = 0; j < 8; ++j) acc[i][j] += a[i] * bb[j];
    }
  }

#pragma unroll
  for (int i = 0; i < 8; ++i)
#pragma unroll
    for (int j = 0; j < 8; ++j) acc[i][j] = 2.f * acc[i][j] - xn[i] - xm[j];

#pragma unroll
  for (int i = 0; i < 8; ++i) {
    int n = n0 + ((i < 4) ? ((ty << 2) + i) : (64 + (ty << 2) + i - 4));
    float* dr = dist + (((size_t)b * NN + n) << 10);
    *(float4*)(dr + m0 + (tx << 2)) =
        make_float4(acc[i][0], acc[i][1], acc[i][2], acc[i][3]);
    *(float4*)(dr + m0 + 64 + (tx << 2)) =
        make_float4(acc[i][4], acc[i][5], acc[i][6], acc[i][7]);
  }

  if (bi != bj) {
#pragma unroll
    for (int j = 0; j < 8; ++j) {
      int m = m0 + ((j < 4) ? ((tx << 2) + j) : (64 + (tx << 2) + j - 4));
      float* dr = dist + (((size_t)b * NN + m) << 10);
      *(float4*)(dr + n0 + (ty << 2)) =
          make_float4(acc[0][j], acc[1][j], acc[2][j], acc[3][j]);
      *(float4*)(dr + n0 + 64 + (ty << 2)) =
          make_float4(acc[4][j], acc[5][j], acc[6][j], acc[7][j]);
    }
  }
}

// ---------------- top-k (k=20) per row, one wave per row ----------------
__device__ __forceinline__ unsigned long long shfl_xor_u64(
    unsigned long long v, int off) {
  unsigned lo = (unsigned)v, hi = (unsigned)(v >> 32);
  lo = __shfl_xor(lo, off, 64);
  hi = __shfl_xor(hi, off, 64);
  return ((unsigned long long)hi << 32) | lo;
}

__global__ __launch_bounds__(256) void topk_kernel(
    const float* __restrict__ dist, int* __restrict__ idx_out) {
  int wave = threadIdx.x >> 6;
  int lane = threadIdx.x & 63;
  int row = blockIdx.x * 4 + wave;
  const float* d = dist + ((size_t)row << 10);

  unsigned long long key[16];
#pragma unroll
  for (int s = 0; s < 16; ++s) {
    int m = lane + (s << 6);
    unsigned u = __float_as_uint(d[m]);
    u = (u & 0x80000000u) ? ~u : (u | 0x80000000u);
    key[s] = ((unsigned long long)u << 32) | (unsigned)(NN - 1 - m);
  }

#pragma unroll
  for (int size = 2; size <= 16; size <<= 1) {
#pragma unroll
    for (int stride = size >> 1; stride > 0; stride >>= 1) {
#pragma unroll
      for (int i = 0; i < 16; ++i) {
        int j = i ^ stride;
        if (j > i) {
          unsigned long long a = key[i], c = key[j];
          bool desc = ((i & size) == 0);
          bool sw = desc ? (a < c) : (a > c);
          key[i] = sw ? c : a;
          key[j] = sw ? a : c;
        }
      }
    }
  }

  int* out = idx_out + row * KK;
  unsigned long long head = key[0];
  for (int r = 0; r < KK; ++r) {
    unsigned long long w = head;
#pragma unroll
    for (int off = 32; off > 0; off >>= 1) {
      unsigned long long o = shfl_xor_u64(w, off);
      if (o > w) w = o;
    }
    if (lane == 0) out[r] = (NN - 1) - (int)(w & 0xFFFFFFFFull);
    if (head == w) {
#pragma unroll
      for (int s = 0; s < 15; ++s) key[s] = key[s + 1];
      key[15] = 0ull;
      head = key[0];
    }
  }
}

// ---------------- fused transform + edge combine + mean over k --------------
// R8 version: 256 threads, n-split grid.y, phase A templated on D.
template <int DD>
__global__ __launch_bounds__(256) void edge_fused_kernel(
    const float* __restrict__ src, int bs, int Co, int nsplit,
    const float* __restrict__ Wf, const float* __restrict__ Wd,
    const int* __restrict__ idx, int ooff, float* __restrict__ xcat) {
  __shared__ float2 Ulds[3 * NN];  // 24 KB {Uf,Ud}
  __shared__ float2 Vlds[3 * NN];  // 24 KB {Vf,Vd}
  __shared__ float4 Wlds[48];      // {wfa, wfb, wda, wdb} per i, DD<=42
  int bo = blockIdx.x;
  int b = bo / Co, o = bo % Co;
  int t = threadIdx.x;

  if (t < DD) {
    float wfa = Wf[o * 2 * DD + t];
    float wfb = Wf[o * 2 * DD + DD + t] - wfa;
    float wda = Wd[o * 2 * DD + t];
    float wdb = Wd[o * 2 * DD + DD + t] - wda;
    Wlds[t] = make_float4(wfa, wfb, wda, wdb);
  }
  __syncthreads();

  const float* sb = src + (size_t)b * bs;
  {
    int c0 = t << 2;
    float4 uf[3], vf[3], ud[3], vd[3];
#pragma unroll
    for (int r = 0; r < 3; ++r) {
      uf[r] = make_float4(0.f, 0.f, 0.f, 0.f);
      vf[r] = make_float4(0.f, 0.f, 0.f, 0.f);
      ud[r] = make_float4(0.f, 0.f, 0.f, 0.f);
      vd[r] = make_float4(0.f, 0.f, 0.f, 0.f);
    }
#pragma unroll 2
    for (int i = 0; i < DD; ++i) {
      const float* row = sb + (size_t)i * 3 * NN + c0;
      float4 s[3];
      s[0] = *(const float4*)(row);
      s[1] = *(const float4*)(row + 1024);
      s[2] = *(const float4*)(row + 2048);
      float4 w = Wlds[i];
#pragma unroll
      for (int r = 0; r < 3; ++r) {
        uf[r].x += w.x * s[r].x; uf[r].y += w.x * s[r].y;
        uf[r].z += w.x * s[r].z; uf[r].w += w.x * s[r].w;
        vf[r].x += w.y * s[r].x; vf[r].y += w.y * s[r].y;
        vf[r].z += w.y * s[r].z; vf[r].w += w.y * s[r].w;
        ud[r].x += w.z * s[r].x; ud[r].y += w.z * s[r].y;
        ud[r].z += w.z * s[r].z; ud[r].w += w.z * s[r].w;
        vd[r].x += w.w * s[r].x; vd[r].y += w.w * s[r].y;
        vd[r].z += w.w * s[r].z; vd[r].w += w.w * s[r].w;
      }
    }
#pragma unroll
    for (int r = 0; r < 3; ++r) {
      int g = t + 256 * r;
      *(float4*)&Ulds[(g << 2) + 0] =
          make_float4(uf[r].x, ud[r].x, uf[r].y, ud[r].y);
      *(float4*)&Ulds[(g << 2) + 2] =
          make_float4(uf[r].z, ud[r].z, uf[r].w, ud[r].w);
      *(float4*)&Vlds[(g << 2) + 0] =
          make_float4(vf[r].x, vd[r].x, vf[r].y, vd[r].y);
      *(float4*)&Vlds[(g << 2) + 2] =
          make_float4(vf[r].z, vd[r].z, vf[r].w, vd[r].w);
    }
  }
  __syncthreads();

  const float inv_k = 1.f / KK;
  int cnt = NN / nsplit;
  int nbase = blockIdx.y * cnt;
  for (int n = nbase + t; n < nbase + cnt; n += 256) {
    float2 v0 = Vlds[n];
    float2 v1 = Vlds[NN + n];
    float2 v2 = Vlds[2 * NN + n];
    const int4* ip = (const int4*)(idx + (b * NN + n) * KK);
    float a0 = 0.f, a1 = 0.f, a2 = 0.f;
#pragma unroll
    for (int q = 0; q < 5; ++q) {
      int4 iv = ip[q];
      int nbs[4] = {iv.x, iv.y, iv.z, iv.w};
#pragma unroll
      for (int jj = 0; jj < 4; ++jj) {
        int nb = nbs[jj];
        float2 u0 = Ulds[nb];
        float2 u1 = Ulds[NN + nb];
        float2 u2 = Ulds[2 * NN + nb];
        float pf0 = u0.x + v0.x, pd0 = u0.y + v0.y;
        float pf1 = u1.x + v1.x, pd1 = u1.y + v1.y;
        float pf2 = u2.x + v2.x, pd2 = u2.y + v2.y;
        float dot = pf0 * pd0 + pf1 * pd1 + pf2 * pd2;
        float dsq = pd0 * pd0 + pd1 * pd1 + pd2 * pd2;
        float g = (dot >= 0.f) ? 0.f : 0.8f * dot / (dsq + 1e-6f);
        a0 += pf0 - g * pd0;
        a1 += pf1 - g * pd1;
        a2 += pf2 - g * pd2;
      }
    }
    size_t ob = (size_t)b * CCAT * 3 * NN + (size_t)(ooff + o) * 3 * NN + n;
    xcat[ob] = a0 * inv_k;
    xcat[ob + NN] = a1 * inv_k;
    xcat[ob + 2 * NN] = a2 * inv_k;
  }
}

// ---------------- prep: transpose Wf4 -> Wt[176][384] (zero-padded), zero pad
// Runs after the layer loop; lives in the dead dist region.
__global__ __launch_bounds__(256) void prep_kernel(
    const float* __restrict__ Wf4, float* __restrict__ Wt,
    float* __restrict__ zpad) {
  int o = blockIdx.x * 256 + threadIdx.x;  // 0..511
  int f = blockIdx.y;                      // 0..175
  if (o < WTLD)
    Wt[(size_t)f * WTLD + o] = (f < CCAT && o < 341) ? Wf4[o * CCAT + f] : 0.f;
  if (blockIdx.x == 0 && blockIdx.y == 0) zpad[threadIdx.x] = 0.f;
}

// ---------------- fused final GEMM + dvec + VN-leakyrelu + partial n-sum ----
// Async-DMA staging (global_load_lds, width 16): staged data never touches
// VGPRs (R1/R3/R9 reg-staged pipelines all spilled). Double-buffered LDS,
// ONE barrier per tile; DMA for tile t+1 issued post-barrier, lands during
// compute(t), so the barrier's vmcnt(0) drain is free (m97 pattern).
__device__ __forceinline__ void gl2lds16(const float* g, float* l) {
  __builtin_amdgcn_global_load_lds(
      (const __attribute__((address_space(1))) unsigned int*)g,
      (__attribute__((address_space(3))) unsigned int*)l, 16, 0, 0);
}

__global__ __launch_bounds__(256) void final_fused_kernel(
    const float* __restrict__ xcat, const float* __restrict__ Wt,
    const float* __restrict__ Wd4, const float* __restrict__ zpad,
    float* __restrict__ part) {
  __shared__ float Ws[2][16][64];     // [buf][f][o_col]   8.2 KB
  __shared__ float Xs[2][3][16][64];  // [buf][c][f][n]   24.6 KB
  __shared__ float Wda[176];
  int b = blockIdx.z;
  int o0 = blockIdx.y * 64;
  int n0 = blockIdx.x * 64;
  int t = threadIdx.x;
  int tx = t & 15, ty = t >> 4;

  if (t < 176) Wda[t] = (t < CCAT) ? Wd4[t] : 0.f;

  float acc[3][4][4];  // [c][o_i][n_j]
  float dv[3][4];      // [c][n_j]
#pragma unroll
  for (int c = 0; c < 3; ++c) {
#pragma unroll
    for (int i = 0; i < 4; ++i)
#pragma unroll
      for (int j = 0; j < 4; ++j) acc[c][i][j] = 0.f;
#pragma unroll
    for (int j = 0; j < 4; ++j) dv[c][j] = 0.f;
  }

  const float* xb = xcat + (size_t)b * CCAT * 3 * NN;
  const int NTILE = 11;  // 176 = 11*16 padded K

  // prologue: issue DMA for tile 0 into buf 0
  {
    const float* wsrc = Wt + (size_t)ty * WTLD + o0 + (tx << 2);
    gl2lds16(wsrc, &Ws[0][ty][tx << 2]);
#pragma unroll
    for (int c = 0; c < 3; ++c) {
      const float* xsrc = xb + ((size_t)ty * 3 + c) * NN + n0 + (tx << 2);
      gl2lds16(xsrc, &Xs[0][c][ty][tx << 2]);
    }
  }

#pragma unroll 1
  for (int tt = 0; tt < NTILE; ++tt) {
    int buf = tt & 1;
    __syncthreads();  // vmcnt(0)+barrier: tile tt landed; buf^1 consumers done
    if (tt + 1 < NTILE) {
      int f = (tt + 1) * 16 + ty;
      const float* wsrc = Wt + (size_t)f * WTLD + o0 + (tx << 2);
      gl2lds16(wsrc, &Ws[buf ^ 1][ty][tx << 2]);
#pragma unroll
      for (int c = 0; c < 3; ++c) {
        const float* xsrc = (f < CCAT)
                                ? xb + ((size_t)f * 3 + c) * NN + n0 + (tx << 2)
                                : zpad + (tx << 2);
        gl2lds16(xsrc, &Xs[buf ^ 1][c][ty][tx << 2]);
      }
    }
#pragma unroll
    for (int f2 = 0; f2 < 16; ++f2) {
      float4 w = *(const float4*)&Ws[buf][f2][ty << 2];
      float wa[4] = {w.x, w.y, w.z, w.w};
      float wd = Wda[tt * 16 + f2];
#pragma unroll
      for (int c = 0; c < 3; ++c) {
        float4 x = *(const float4*)&Xs[buf][c][f2][tx << 2];
        float xa[4] = {x.x, x.y, x.z, x.w};
#pragma unroll
        for (int j = 0; j < 4; ++j) dv[c][j] += wd * xa[j];
#pragma unroll
        for (int i = 0; i < 4; ++i)
#pragma unroll
          for (int j = 0; j < 4; ++j) acc[c][i][j] += wa[i] * xa[j];
      }
    }
  }

  float s[3][4];
#pragma unroll
  for (int c = 0; c < 3; ++c)
#pragma unroll
    for (int i = 0; i < 4; ++i) s[c][i] = 0.f;
#pragma unroll
  for (int i = 0; i < 4; ++i) {
#pragma unroll
    for (int j = 0; j < 4; ++j) {
      float d0 = dv[0][j], d1 = dv[1][j], d2 = dv[2][j];
      float p0 = acc[0][i][j], p1 = acc[1][i][j], p2 = acc[2][i][j];
      float dot = p0 * d0 + p1 * d1 + p2 * d2;
      float dsq = d0 * d0 + d1 * d1 + d2 * d2;
      float g = (dot >= 0.f) ? 0.f : 0.8f * dot / (dsq + 1e-6f);
      s[0][i] += p0 - g * d0;
      s[1][i] += p1 - g * d1;
      s[2][i] += p2 - g * d2;
    }
  }

#pragma unroll
  for (int off = 1; off < 16; off <<= 1) {
#pragma unroll
    for (int c = 0; c < 3; ++c)
#pragma unroll
      for (int i = 0; i < 4; ++i) s[c][i] += __shfl_xor(s[c][i], off, 64);
  }
  if (tx == 0) {
#pragma unroll
    for (int i = 0; i < 4; ++i) {
      int o = o0 + (ty << 2) + i;
      if (o < 341) {
#pragma unroll
        for (int c = 0; c < 3; ++c)
          part[(((size_t)b * 341 + o) * 3 + c) * NT + blockIdx.x] = s[c][i];
      }
    }
  }
}

__global__ void final_reduce_kernel(const float* __restrict__ part,
                                    float* __restrict__ out) {
  int t = blockIdx.x * 256 + threadIdx.x;
  if (t >= BB * 341 * 3) return;
  const float* p = part + (size_t)t * NT;
  float s = 0.f;
#pragma unroll
  for (int nt = 0; nt < NT; ++nt) s += p[nt];
  out[t] = s * (1.f / 1024.f);
}

extern "C" void kernel_launch(void* const* d_in, const int* in_sizes, int n_in,
                              void* d_out, int out_size, void* d_ws,
                              size_t ws_size, hipStream_t stream) {
  (void)in_sizes; (void)n_in; (void)out_size; (void)ws_size;
  const float* x = (const float*)d_in[0];
  const float* Wf[5] = {(const float*)d_in[1], (const float*)d_in[3],
                        (const float*)d_in[5], (const float*)d_in[7],
                        (const float*)d_in[9]};
  const float* Wd[5] = {(const float*)d_in[2], (const float*)d_in[4],
                        (const float*)d_in[6], (const float*)d_in[8],
                        (const float*)d_in[10]};

  float* ws = (float*)d_ws;
  float* dist = ws;
  // Final phase overlays the dead dist region:
  //   part at ws+0 (131,328 floats), Wt at ws+262144 (67,584), zpad after it.
  float* part = ws;
  float* Wt = ws + 262144;
  float* zpad = Wt + 176 * WTLD;
  size_t off = (size_t)BB * NN * NN;
  int* idx = (int*)(ws + off);
  off += (size_t)BB * NN * KK;
  float* xcat = ws + off;

  struct LayerCfg { int D, Co, inoff, ooff, nsplit; };
  const LayerCfg L[4] = {
      {1, 21, 0, 0, 4},
      {21, 21, 0, 21, 4},
      {21, 42, 21, 42, 2},
      {42, 85, 42, 84, 1},
  };

  for (int l = 0; l < 4; ++l) {
    const float* src = (l == 0) ? x : (xcat + (size_t)L[l].inoff * 3 * NN);
    int bs = (l == 0) ? 3 * NN : CCAT * 3 * NN;
    int D = L[l].D, Co = L[l].Co;

    dist_tile_kernel<<<dim3(36, 1, BB), 256, 0, stream>>>(src, bs, 3 * D, dist);
    topk_kernel<<<(BB * NN) / 4, 256, 0, stream>>>(dist, idx);
    dim3 eg(BB * Co, L[l].nsplit);
    if (D == 1)
      edge_fused_kernel<1><<<eg, 256, 0, stream>>>(
          src, bs, Co, L[l].nsplit, Wf[l], Wd[l], idx, L[l].ooff, xcat);
    else if (D == 21)
      edge_fused_kernel<21><<<eg, 256, 0, stream>>>(
          src, bs, Co, L[l].nsplit, Wf[l], Wd[l], idx, L[l].ooff, xcat);
    else
      edge_fused_kernel<42><<<eg, 256, 0, stream>>>(
          src, bs, Co, L[l].nsplit, Wf[l], Wd[l], idx, L[l].ooff, xcat);
  }

  prep_kernel<<<dim3(2, 176), 256, 0, stream>>>(Wf[4], Wt, zpad);
  final_fused_kernel<<<dim3(NT, 6, BB), 256, 0, stream>>>(xcat, Wt, Wd[4],
                                                          zpad, part);
  final_reduce_kernel<<<(BB * 341 * 3 + 255) / 256, 256, 0, stream>>>(
      part, (float*)d_out);
}

// Round 11
// 426.730 us; speedup vs baseline: 1.0895x; 1.0006x over previous
//
#include <hip/hip_runtime.h>
#include <cstddef>

#define BB 8
#define NN 1024
#define KK 20
#define CCAT 169
#define NT 16   // n-tiles of 64 in final fused GEMM
#define WTLD 384  // padded row length of transposed Wf4

// ---------------- neg dist, symmetric triangle tiles, norms fused in --------
// dist[b][n][m] = 2*sum_f x[f][n]*x[f][m] - ||x_n||^2 - ||x_m||^2  (symmetric)
__global__ __launch_bounds__(256) void dist_tile_kernel(
    const float* __restrict__ src, int bs, int F, float* __restrict__ dist) {
  __shared__ float As[8][128];
  __shared__ float Bs[8][128];
  int b = blockIdx.z;
  int rem = blockIdx.x, bi = 0;
  while (rem >= 8 - bi) { rem -= 8 - bi; ++bi; }
  int bj = bi + rem;
  int n0 = bi * 128;
  int m0 = bj * 128;
  int t = threadIdx.x;
  int tx = t & 15, ty = t >> 4;
  const float* p = src + (size_t)b * bs;

  float acc[8][8];
  float xn[8], xm[8];
#pragma unroll
  for (int i = 0; i < 8; ++i) {
    xn[i] = 0.f;
    xm[i] = 0.f;
#pragma unroll
    for (int j = 0; j < 8; ++j) acc[i][j] = 0.f;
  }

  int fr = t >> 5;
  int cc = (t & 31) << 2;
  for (int f0 = 0; f0 < F; f0 += 8) {
    int f = f0 + fr;
    float4 av = {0.f, 0.f, 0.f, 0.f}, bv = {0.f, 0.f, 0.f, 0.f};
    if (f < F) {
      av = *(const float4*)(p + (size_t)f * NN + n0 + cc);
      bv = *(const float4*)(p + (size_t)f * NN + m0 + cc);
    }
    __syncthreads();
    *(float4*)&As[fr][cc] = av;
    *(float4*)&Bs[fr][cc] = bv;
    __syncthreads();
#pragma unroll
    for (int f2 = 0; f2 < 8; ++f2) {
      float4 al = *(const float4*)&As[f2][ty << 2];
      float4 ah = *(const float4*)&As[f2][64 + (ty << 2)];
      float4 bl = *(const float4*)&Bs[f2][tx << 2];
      float4 bh = *(const float4*)&Bs[f2][64 + (tx << 2)];
      float a[8] = {al.x, al.y, al.z, al.w, ah.x, ah.y, ah.z, ah.w};
      float bb[8] = {bl.x, bl.y, bl.z, bl.w, bh.x, bh.y, bh.z, bh.w};
#pragma unroll
      for (int i = 0; i < 8; ++i) xn[i] += a[i] * a[i];
#pragma unroll
      for (int j = 0; j < 8; ++j) xm[j] += bb[j] * bb[j];
#pragma unroll
      for (int i = 0; i < 8; ++i)
#pragma unroll
        for (int j = 0; j < 8; ++j) acc[i][j] += a[i] * bb[j];
    }
  }

#pragma unroll
  for (int i = 0; i < 8; ++i)
#pragma unroll
    for (int j = 0; j < 8; ++j) acc[i][j] = 2.f * acc[i][j] - xn[i] - xm[j];

#pragma unroll
  for (int i = 0; i < 8; ++i) {
    int n = n0 + ((i < 4) ? ((ty << 2) + i) : (64 + (ty << 2) + i - 4));
    float* dr = dist + (((size_t)b * NN + n) << 10);
    *(float4*)(dr + m0 + (tx << 2)) =
        make_float4(acc[i][0], acc[i][1], acc[i][2], acc[i][3]);
    *(float4*)(dr + m0 + 64 + (tx << 2)) =
        make_float4(acc[i][4], acc[i][5], acc[i][6], acc[i][7]);
  }

  if (bi != bj) {
#pragma unroll
    for (int j = 0; j < 8; ++j) {
      int m = m0 + ((j < 4) ? ((tx << 2) + j) : (64 + (tx << 2) + j - 4));
      float* dr = dist + (((size_t)b * NN + m) << 10);
      *(float4*)(dr + n0 + (ty << 2)) =
          make_float4(acc[0][j], acc[1][j], acc[2][j], acc[3][j]);
      *(float4*)(dr + n0 + 64 + (ty << 2)) =
          make_float4(acc[4][j], acc[5][j], acc[6][j], acc[7][j]);
    }
  }
}

// ---------------- top-k (k=20) per row, one wave per row ----------------
// Keys: hi32 = order-preserving float->uint map, lo32 = (1023-m) so ties
// break toward LOWER index (jax.lax.top_k semantics). All keys unique.
// Per-lane bitonic sort once, then 20 tournament rounds. Rounds reduce on
// the 32-bit VALUE only (6x {shfl+max}); index resolved via ballot + shfl;
// the lexicographic low-word reduce runs only on a value tie (~never).
__global__ __launch_bounds__(256) void topk_kernel(
    const float* __restrict__ dist, int* __restrict__ idx_out) {
  int wave = threadIdx.x >> 6;
  int lane = threadIdx.x & 63;
  int row = blockIdx.x * 4 + wave;
  const float* d = dist + ((size_t)row << 10);

  unsigned long long key[16];
  {
    const float4* dp = (const float4*)(d + (lane << 4));
#pragma unroll
    for (int q = 0; q < 4; ++q) {
      float4 v4 = dp[q];
      float vv[4] = {v4.x, v4.y, v4.z, v4.w};
#pragma unroll
      for (int e = 0; e < 4; ++e) {
        int m = (lane << 4) + (q << 2) + e;
        unsigned u = __float_as_uint(vv[e]);
        u = (u & 0x80000000u) ? ~u : (u | 0x80000000u);
        key[(q << 2) + e] =
            ((unsigned long long)u << 32) | (unsigned)(NN - 1 - m);
      }
    }
  }

  // bitonic sort, descending (compile-time indices -> stays in VGPRs)
#pragma unroll
  for (int size = 2; size <= 16; size <<= 1) {
#pragma unroll
    for (int stride = size >> 1; stride > 0; stride >>= 1) {
#pragma unroll
      for (int i = 0; i < 16; ++i) {
        int j = i ^ stride;
        if (j > i) {
          unsigned long long a = key[i], c = key[j];
          bool desc = ((i & size) == 0);
          bool sw = desc ? (a < c) : (a > c);
          key[i] = sw ? c : a;
          key[j] = sw ? a : c;
        }
      }
    }
  }

  int* out = idx_out + row * KK;
  unsigned long long head = key[0];
  for (int r = 0; r < KK; ++r) {
    unsigned hv = (unsigned)(head >> 32);
    unsigned v = hv;
#pragma unroll
    for (int off = 32; off > 0; off >>= 1) {
      unsigned o = __shfl_xor(v, off, 64);
      v = (o > v) ? o : v;
    }
    unsigned long long tie = __ballot(hv == v);
    unsigned il;
    if (tie & (tie - 1)) {  // >=2 lanes tie in value: reduce low word
      unsigned c = (hv == v) ? (unsigned)head : 0u;
#pragma unroll
      for (int off = 32; off > 0; off >>= 1) {
        unsigned o = __shfl_xor(c, off, 64);
        c = (o > c) ? o : c;
      }
      il = c;
    } else {
      int wl = __builtin_ctzll(tie);
      il = __shfl((unsigned)head, wl, 64);
    }
    if (lane == 0) out[r] = (NN - 1) - (int)il;
    if (hv == v && (unsigned)head == il) {  // unique winner pops its head
#pragma unroll
      for (int s = 0; s < 15; ++s) key[s] = key[s + 1];
      key[15] = 0ull;  // sentinel: below every real key, can't tie
      head = key[0];
    }
  }
}

// ---------------- fused transform + edge combine + mean over k --------------
// R8 version: 256 threads, n-split grid.y, phase A templated on D.
template <int DD>
__global__ __launch_bounds__(256) void edge_fused_kernel(
    const float* __restrict__ src, int bs, int Co, int nsplit,
    const float* __restrict__ Wf, const float* __restrict__ Wd,
    const int* __restrict__ idx, int ooff, float* __restrict__ xcat) {
  __shared__ float2 Ulds[3 * NN];  // 24 KB {Uf,Ud}
  __shared__ float2 Vlds[3 * NN];  // 24 KB {Vf,Vd}
  __shared__ float4 Wlds[48];      // {wfa, wfb, wda, wdb} per i, DD<=42
  int bo = blockIdx.x;
  int b = bo / Co, o = bo % Co;
  int t = threadIdx.x;

  if (t < DD) {
    float wfa = Wf[o * 2 * DD + t];
    float wfb = Wf[o * 2 * DD + DD + t] - wfa;
    float wda = Wd[o * 2 * DD + t];
    float wdb = Wd[o * 2 * DD + DD + t] - wda;
    Wlds[t] = make_float4(wfa, wfb, wda, wdb);
  }
  __syncthreads();

  const float* sb = src + (size_t)b * bs;
  {
    int c0 = t << 2;
    float4 uf[3], vf[3], ud[3], vd[3];
#pragma unroll
    for (int r = 0; r < 3; ++r) {
      uf[r] = make_float4(0.f, 0.f, 0.f, 0.f);
      vf[r] = make_float4(0.f, 0.f, 0.f, 0.f);
      ud[r] = make_float4(0.f, 0.f, 0.f, 0.f);
      vd[r] = make_float4(0.f, 0.f, 0.f, 0.f);
    }
#pragma unroll 2
    for (int i = 0; i < DD; ++i) {
      const float* row = sb + (size_t)i * 3 * NN + c0;
      float4 s[3];
      s[0] = *(const float4*)(row);
      s[1] = *(const float4*)(row + 1024);
      s[2] = *(const float4*)(row + 2048);
      float4 w = Wlds[i];
#pragma unroll
      for (int r = 0; r < 3; ++r) {
        uf[r].x += w.x * s[r].x; uf[r].y += w.x * s[r].y;
        uf[r].z += w.x * s[r].z; uf[r].w += w.x * s[r].w;
        vf[r].x += w.y * s[r].x; vf[r].y += w.y * s[r].y;
        vf[r].z += w.y * s[r].z; vf[r].w += w.y * s[r].w;
        ud[r].x += w.z * s[r].x; ud[r].y += w.z * s[r].y;
        ud[r].z += w.z * s[r].z; ud[r].w += w.z * s[r].w;
        vd[r].x += w.w * s[r].x; vd[r].y += w.w * s[r].y;
        vd[r].z += w.w * s[r].z; vd[r].w += w.w * s[r].w;
      }
    }
#pragma unroll
    for (int r = 0; r < 3; ++r) {
      int g = t + 256 * r;
      *(float4*)&Ulds[(g << 2) + 0] =
          make_float4(uf[r].x, ud[r].x, uf[r].y, ud[r].y);
      *(float4*)&Ulds[(g << 2) + 2] =
          make_float4(uf[r].z, ud[r].z, uf[r].w, ud[r].w);
      *(float4*)&Vlds[(g << 2) + 0] =
          make_float4(vf[r].x, vd[r].x, vf[r].y, vd[r].y);
      *(float4*)&Vlds[(g << 2) + 2] =
          make_float4(vf[r].z, vd[r].z, vf[r].w, vd[r].w);
    }
  }
  __syncthreads();

  const float inv_k = 1.f / KK;
  int cnt = NN / nsplit;
  int nbase = blockIdx.y * cnt;
  for (int n = nbase + t; n < nbase + cnt; n += 256) {
    float2 v0 = Vlds[n];
    float2 v1 = Vlds[NN + n];
    float2 v2 = Vlds[2 * NN + n];
    const int4* ip = (const int4*)(idx + (b * NN + n) * KK);
    float a0 = 0.f, a1 = 0.f, a2 = 0.f;
#pragma unroll
    for (int q = 0; q < 5; ++q) {
      int4 iv = ip[q];
      int nbs[4] = {iv.x, iv.y, iv.z, iv.w};
#pragma unroll
      for (int jj = 0; jj < 4; ++jj) {
        int nb = nbs[jj];
        float2 u0 = Ulds[nb];
        float2 u1 = Ulds[NN + nb];
        float2 u2 = Ulds[2 * NN + nb];
        float pf0 = u0.x + v0.x, pd0 = u0.y + v0.y;
        float pf1 = u1.x + v1.x, pd1 = u1.y + v1.y;
        float pf2 = u2.x + v2.x, pd2 = u2.y + v2.y;
        float dot = pf0 * pd0 + pf1 * pd1 + pf2 * pd2;
        float dsq = pd0 * pd0 + pd1 * pd1 + pd2 * pd2;
        float g = (dot >= 0.f) ? 0.f : 0.8f * dot / (dsq + 1e-6f);
        a0 += pf0 - g * pd0;
        a1 += pf1 - g * pd1;
        a2 += pf2 - g * pd2;
      }
    }
    size_t ob = (size_t)b * CCAT * 3 * NN + (size_t)(ooff + o) * 3 * NN + n;
    xcat[ob] = a0 * inv_k;
    xcat[ob + NN] = a1 * inv_k;
    xcat[ob + 2 * NN] = a2 * inv_k;
  }
}

// ---------------- prep: transpose Wf4 -> Wt[176][384] (zero-padded), zero pad
__global__ __launch_bounds__(256) void prep_kernel(
    const float* __restrict__ Wf4, float* __restrict__ Wt,
    float* __restrict__ zpad) {
  int o = blockIdx.x * 256 + threadIdx.x;  // 0..511
  int f = blockIdx.y;                      // 0..175
  if (o < WTLD)
    Wt[(size_t)f * WTLD + o] = (f < CCAT && o < 341) ? Wf4[o * CCAT + f] : 0.f;
  if (blockIdx.x == 0 && blockIdx.y == 0) zpad[threadIdx.x] = 0.f;
}

// ---------------- fused final GEMM + dvec + VN-leakyrelu + partial n-sum ----
// Async-DMA staging (global_load_lds w16): staged data never touches VGPRs.
// Double-buffered LDS, one barrier per tile. ~70 µs — structural limit for
// this structure (barrier vmcnt drain); declared done.
__device__ __forceinline__ void gl2lds16(const float* g, float* l) {
  __builtin_amdgcn_global_load_lds(
      (const __attribute__((address_space(1))) unsigned int*)g,
      (__attribute__((address_space(3))) unsigned int*)l, 16, 0, 0);
}

__global__ __launch_bounds__(256) void final_fused_kernel(
    const float* __restrict__ xcat, const float* __restrict__ Wt,
    const float* __restrict__ Wd4, const float* __restrict__ zpad,
    float* __restrict__ part) {
  __shared__ float Ws[2][16][64];     // [buf][f][o_col]   8.2 KB
  __shared__ float Xs[2][3][16][64];  // [buf][c][f][n]   24.6 KB
  __shared__ float Wda[176];
  int b = blockIdx.z;
  int o0 = blockIdx.y * 64;
  int n0 = blockIdx.x * 64;
  int t = threadIdx.x;
  int tx = t & 15, ty = t >> 4;

  if (t < 176) Wda[t] = (t < CCAT) ? Wd4[t] : 0.f;

  float acc[3][4][4];  // [c][o_i][n_j]
  float dv[3][4];      // [c][n_j]
#pragma unroll
  for (int c = 0; c < 3; ++c) {
#pragma unroll
    for (int i = 0; i < 4; ++i)
#pragma unroll
      for (int j = 0; j < 4; ++j) acc[c][i][j] = 0.f;
#pragma unroll
    for (int j = 0; j < 4; ++j) dv[c][j] = 0.f;
  }

  const float* xb = xcat + (size_t)b * CCAT * 3 * NN;
  const int NTILE = 11;  // 176 = 11*16 padded K

  {
    const float* wsrc = Wt + (size_t)ty * WTLD + o0 + (tx << 2);
    gl2lds16(wsrc, &Ws[0][ty][tx << 2]);
#pragma unroll
    for (int c = 0; c < 3; ++c) {
      const float* xsrc = xb + ((size_t)ty * 3 + c) * NN + n0 + (tx << 2);
      gl2lds16(xsrc, &Xs[0][c][ty][tx << 2]);
    }
  }

#pragma unroll 1
  for (int tt = 0; tt < NTILE; ++tt) {
    int buf = tt & 1;
    __syncthreads();  // vmcnt(0)+barrier: tile tt landed; buf^1 consumers done
    if (tt + 1 < NTILE) {
      int f = (tt + 1) * 16 + ty;
      const float* wsrc = Wt + (size_t)f * WTLD + o0 + (tx << 2);
      gl2lds16(wsrc, &Ws[buf ^ 1][ty][tx << 2]);
#pragma unroll
      for (int c = 0; c < 3; ++c) {
        const float* xsrc = (f < CCAT)
                                ? xb + ((size_t)f * 3 + c) * NN + n0 + (tx << 2)
                                : zpad + (tx << 2);
        gl2lds16(xsrc, &Xs[buf ^ 1][c][ty][tx << 2]);
      }
    }
#pragma unroll
    for (int f2 = 0; f2 < 16; ++f2) {
      float4 w = *(const float4*)&Ws[buf][f2][ty << 2];
      float wa[4] = {w.x, w.y, w.z, w.w};
      float wd = Wda[tt * 16 + f2];
#pragma unroll
      for (int c = 0; c < 3; ++c) {
        float4 x = *(const float4*)&Xs[buf][c][f2][tx << 2];
        float xa[4] = {x.x, x.y, x.z, x.w};
#pragma unroll
        for (int j = 0; j < 4; ++j) dv[c][j] += wd * xa[j];
#pragma unroll
        for (int i = 0; i < 4; ++i)
#pragma unroll
          for (int j = 0; j < 4; ++j) acc[c][i][j] += wa[i] * xa[j];
      }
    }
  }

  float s[3][4];
#pragma unroll
  for (int c = 0; c < 3; ++c)
#pragma unroll
    for (int i = 0; i < 4; ++i) s[c][i] = 0.f;
#pragma unroll
  for (int i = 0; i < 4; ++i) {
#pragma unroll
    for (int j = 0; j < 4; ++j) {
      float d0 = dv[0][j], d1 = dv[1][j], d2 = dv[2][j];
      float p0 = acc[0][i][j], p1 = acc[1][i][j], p2 = acc[2][i][j];
      float dot = p0 * d0 + p1 * d1 + p2 * d2;
      float dsq = d0 * d0 + d1 * d1 + d2 * d2;
      float g = (dot >= 0.f) ? 0.f : 0.8f * dot / (dsq + 1e-6f);
      s[0][i] += p0 - g * d0;
      s[1][i] += p1 - g * d1;
      s[2][i] += p2 - g * d2;
    }
  }

#pragma unroll
  for (int off = 1; off < 16; off <<= 1) {
#pragma unroll
    for (int c = 0; c < 3; ++c)
#pragma unroll
      for (int i = 0; i < 4; ++i) s[c][i] += __shfl_xor(s[c][i], off, 64);
  }
  if (tx == 0) {
#pragma unroll
    for (int i = 0; i < 4; ++i) {
      int o = o0 + (ty << 2) + i;
      if (o < 341) {
#pragma unroll
        for (int c = 0; c < 3; ++c)
          part[(((size_t)b * 341 + o) * 3 + c) * NT + blockIdx.x] = s[c][i];
      }
    }
  }
}

__global__ void final_reduce_kernel(const float* __restrict__ part,
                                    float* __restrict__ out) {
  int t = blockIdx.x * 256 + threadIdx.x;
  if (t >= BB * 341 * 3) return;
  const float* p = part + (size_t)t * NT;
  float s = 0.f;
#pragma unroll
  for (int nt = 0; nt < NT; ++nt) s += p[nt];
  out[t] = s * (1.f / 1024.f);
}

extern "C" void kernel_launch(void* const* d_in, const int* in_sizes, int n_in,
                              void* d_out, int out_size, void* d_ws,
                              size_t ws_size, hipStream_t stream) {
  (void)in_sizes; (void)n_in; (void)out_size; (void)ws_size;
  const float* x = (const float*)d_in[0];
  const float* Wf[5] = {(const float*)d_in[1], (const float*)d_in[3],
                        (const float*)d_in[5], (const float*)d_in[7],
                        (const float*)d_in[9]};
  const float* Wd[5] = {(const float*)d_in[2], (const float*)d_in[4],
                        (const float*)d_in[6], (const float*)d_in[8],
                        (const float*)d_in[10]};

  float* ws = (float*)d_ws;
  float* dist = ws;
  float* part = ws;
  float* Wt = ws + 262144;
  float* zpad = Wt + 176 * WTLD;
  size_t off = (size_t)BB * NN * NN;
  int* idx = (int*)(ws + off);
  off += (size_t)BB * NN * KK;
  float* xcat = ws + off;

  struct LayerCfg { int D, Co, inoff, ooff, nsplit; };
  const LayerCfg L[4] = {
      {1, 21, 0, 0, 4},
      {21, 21, 0, 21, 4},
      {21, 42, 21, 42, 2},
      {42, 85, 42, 84, 1},
  };

  for (int l = 0; l < 4; ++l) {
    const float* src = (l == 0) ? x : (xcat + (size_t)L[l].inoff * 3 * NN);
    int bs = (l == 0) ? 3 * NN : CCAT * 3 * NN;
    int D = L[l].D, Co = L[l].Co;

    dist_tile_kernel<<<dim3(36, 1, BB), 256, 0, stream>>>(src, bs, 3 * D, dist);
    topk_kernel<<<(BB * NN) / 4, 256, 0, stream>>>(dist, idx);
    dim3 eg(BB * Co, L[l].nsplit);
    if (D == 1)
      edge_fused_kernel<1><<<eg, 256, 0, stream>>>(
          src, bs, Co, L[l].nsplit, Wf[l], Wd[l], idx, L[l].ooff, xcat);
    else if (D == 21)
      edge_fused_kernel<21><<<eg, 256, 0, stream>>>(
          src, bs, Co, L[l].nsplit, Wf[l], Wd[l], idx, L[l].ooff, xcat);
    else
      edge_fused_kernel<42><<<eg, 256, 0, stream>>>(
          src, bs, Co, L[l].nsplit, Wf[l], Wd[l], idx, L[l].ooff, xcat);
  }

  prep_kernel<<<dim3(2, 176), 256, 0, stream>>>(Wf[4], Wt, zpad);
  final_fused_kernel<<<dim3(NT, 6, BB), 256, 0, stream>>>(xcat, Wt, Wd[4],
                                                          zpad, part);
  final_reduce_kernel<<<(BB * 341 * 3 + 255) / 256, 256, 0, stream>>>(
      part, (float*)d_out);
}

// Round 12
// 394.949 us; speedup vs baseline: 1.1772x; 1.0805x over previous
//
#include <hip/hip_runtime.h>
#include <cstddef>

#define BB 8
#define NN 1024
#define KK 20
#define CCAT 169
#define NT 16   // n-tiles of 64 in final fused GEMM
#define WTLD 384  // padded row length of transposed Wf4

// ---------------- neg dist, full grid, F-templated, double-buffered ---------
// dist[b][n][m] = 2*sum_f x[f][n]*x[f][m] - ||x_n||^2 - ||x_m||^2
// Dbuf: loads for tile k+1 issued right after the barrier; their vmcnt wait
// lands at the post-compute LDS store, hiding global latency under 512 FMAs
// (the old single-buffer hit vmcnt(0) at the barrier immediately after issue).
// Full 64-tile grid (512 blocks/launch): R2's symmetry halved the grid for
// no measurable gain; parallelism matters more at 1-2 blocks/CU.
template <int F>
__global__ __launch_bounds__(256) void dist_tile_kernel(
    const float* __restrict__ src, int bs, float* __restrict__ dist) {
  __shared__ float As[2][8][128];
  __shared__ float Bs[2][8][128];
  int b = blockIdx.z;
  int n0 = blockIdx.y * 128;
  int m0 = blockIdx.x * 128;
  int t = threadIdx.x;
  int tx = t & 15, ty = t >> 4;
  const float* p = src + (size_t)b * bs;

  float acc[8][8];
  float xn[8], xm[8];
#pragma unroll
  for (int i = 0; i < 8; ++i) {
    xn[i] = 0.f;
    xm[i] = 0.f;
#pragma unroll
    for (int j = 0; j < 8; ++j) acc[i][j] = 0.f;
  }

  int fr = t >> 5;
  int cc = (t & 31) << 2;
  constexpr int T = (F + 7) / 8;

  float4 av = {0.f, 0.f, 0.f, 0.f}, bv = {0.f, 0.f, 0.f, 0.f};
  if (fr < F) {  // tile 0
    av = *(const float4*)(p + (size_t)fr * NN + n0 + cc);
    bv = *(const float4*)(p + (size_t)fr * NN + m0 + cc);
  }
  *(float4*)&As[0][fr][cc] = av;
  *(float4*)&Bs[0][fr][cc] = bv;

#pragma unroll 1
  for (int k = 0; k < T; ++k) {
    __syncthreads();  // tile k staged; buf^1 consumers (tile k-1) done
    if (k + 1 < T) {
      int f = (k + 1) * 8 + fr;
      av = make_float4(0.f, 0.f, 0.f, 0.f);
      bv = make_float4(0.f, 0.f, 0.f, 0.f);
      if (f < F) {
        av = *(const float4*)(p + (size_t)f * NN + n0 + cc);
        bv = *(const float4*)(p + (size_t)f * NN + m0 + cc);
      }
    }
    const float(*A)[128] = As[k & 1];
    const float(*B)[128] = Bs[k & 1];
#pragma unroll
    for (int f2 = 0; f2 < 8; ++f2) {
      float4 al = *(const float4*)&A[f2][ty << 2];
      float4 ah = *(const float4*)&A[f2][64 + (ty << 2)];
      float4 bl = *(const float4*)&B[f2][tx << 2];
      float4 bh = *(const float4*)&B[f2][64 + (tx << 2)];
      float a[8] = {al.x, al.y, al.z, al.w, ah.x, ah.y, ah.z, ah.w};
      float bb[8] = {bl.x, bl.y, bl.z, bl.w, bh.x, bh.y, bh.z, bh.w};
#pragma unroll
      for (int i = 0; i < 8; ++i) xn[i] += a[i] * a[i];
#pragma unroll
      for (int j = 0; j < 8; ++j) xm[j] += bb[j] * bb[j];
#pragma unroll
      for (int i = 0; i < 8; ++i)
#pragma unroll
        for (int j = 0; j < 8; ++j) acc[i][j] += a[i] * bb[j];
    }
    if (k + 1 < T) {
      *(float4*)&As[(k + 1) & 1][fr][cc] = av;  // vmcnt wait lands HERE
      *(float4*)&Bs[(k + 1) & 1][fr][cc] = bv;
    }
  }

#pragma unroll
  for (int i = 0; i < 8; ++i)
#pragma unroll
    for (int j = 0; j < 8; ++j) acc[i][j] = 2.f * acc[i][j] - xn[i] - xm[j];

#pragma unroll
  for (int i = 0; i < 8; ++i) {
    int n = n0 + ((i < 4) ? ((ty << 2) + i) : (64 + (ty << 2) + i - 4));
    float* dr = dist + (((size_t)b * NN + n) << 10);
    *(float4*)(dr + m0 + (tx << 2)) =
        make_float4(acc[i][0], acc[i][1], acc[i][2], acc[i][3]);
    *(float4*)(dr + m0 + 64 + (tx << 2)) =
        make_float4(acc[i][4], acc[i][5], acc[i][6], acc[i][7]);
  }
}

// ---------------- top-k (k=20) per row, one wave per row ----------------
// Keys: hi32 = order-preserving float->uint map, lo32 = (1023-m): ties break
// toward LOWER index (jax semantics); all keys unique. Per-lane bitonic sort
// once; sorted tail spilled to an LDS queue ([wave][slot][lane]: 64 lanes x
// b64 = 2-way bank = free). Pop = one single-lane ds_read_b64 (replaces the
// 30-mov divergent register shift, ~600 instr/wave). Tournament reduces on
// the 32-bit value; index via ballot+shfl; low-word reduce only on tie.
__global__ __launch_bounds__(256) void topk_kernel(
    const float* __restrict__ dist, int* __restrict__ idx_out) {
  __shared__ unsigned long long q[4][16][64];  // 32 KB
  int wave = threadIdx.x >> 6;
  int lane = threadIdx.x & 63;
  int row = blockIdx.x * 4 + wave;
  const float* d = dist + ((size_t)row << 10);

  unsigned long long key[16];
  {
    const float4* dp = (const float4*)(d + (lane << 4));
#pragma unroll
    for (int qd = 0; qd < 4; ++qd) {
      float4 v4 = dp[qd];
      float vv[4] = {v4.x, v4.y, v4.z, v4.w};
#pragma unroll
      for (int e = 0; e < 4; ++e) {
        int m = (lane << 4) + (qd << 2) + e;
        unsigned u = __float_as_uint(vv[e]);
        u = (u & 0x80000000u) ? ~u : (u | 0x80000000u);
        key[(qd << 2) + e] =
            ((unsigned long long)u << 32) | (unsigned)(NN - 1 - m);
      }
    }
  }

  // bitonic sort, descending (compile-time indices -> stays in VGPRs)
#pragma unroll
  for (int size = 2; size <= 16; size <<= 1) {
#pragma unroll
    for (int stride = size >> 1; stride > 0; stride >>= 1) {
#pragma unroll
      for (int i = 0; i < 16; ++i) {
        int j = i ^ stride;
        if (j > i) {
          unsigned long long a = key[i], c = key[j];
          bool desc = ((i & size) == 0);
          bool sw = desc ? (a < c) : (a > c);
          key[i] = sw ? c : a;
          key[j] = sw ? a : c;
        }
      }
    }
  }

  // spill sorted tail (slots 1..15) + sentinel; head stays in register
#pragma unroll
  for (int s = 1; s < 16; ++s) q[wave][s - 1][lane] = key[s];
  q[wave][15][lane] = 0ull;  // sentinel: below every real key, can't tie

  int* out = idx_out + row * KK;
  unsigned long long head = key[0];
  int ptr = 0;
  for (int r = 0; r < KK; ++r) {
    unsigned hv = (unsigned)(head >> 32);
    unsigned v = hv;
#pragma unroll
    for (int off = 32; off > 0; off >>= 1) {
      unsigned o = __shfl_xor(v, off, 64);
      v = (o > v) ? o : v;
    }
    unsigned long long tie = __ballot(hv == v);
    unsigned il;
    if (tie & (tie - 1)) {  // >=2 lanes tie in value: reduce low word
      unsigned c = (hv == v) ? (unsigned)head : 0u;
#pragma unroll
      for (int off = 32; off > 0; off >>= 1) {
        unsigned o = __shfl_xor(c, off, 64);
        c = (o > c) ? o : c;
      }
      il = c;
    } else {
      int wl = __builtin_ctzll(tie);
      il = __shfl((unsigned)head, wl, 64);
    }
    if (lane == 0) out[r] = (NN - 1) - (int)il;
    if (hv == v && (unsigned)head == il) {  // unique winner pops from LDS
      head = q[wave][ptr][lane];
      ++ptr;
    }
  }
}

// ---------------- fused transform + edge combine + mean over k --------------
// R8 version: 256 threads, n-split grid.y, phase A templated on D.
template <int DD>
__global__ __launch_bounds__(256) void edge_fused_kernel(
    const float* __restrict__ src, int bs, int Co, int nsplit,
    const float* __restrict__ Wf, const float* __restrict__ Wd,
    const int* __restrict__ idx, int ooff, float* __restrict__ xcat) {
  __shared__ float2 Ulds[3 * NN];  // 24 KB {Uf,Ud}
  __shared__ float2 Vlds[3 * NN];  // 24 KB {Vf,Vd}
  __shared__ float4 Wlds[48];      // {wfa, wfb, wda, wdb} per i, DD<=42
  int bo = blockIdx.x;
  int b = bo / Co, o = bo % Co;
  int t = threadIdx.x;

  if (t < DD) {
    float wfa = Wf[o * 2 * DD + t];
    float wfb = Wf[o * 2 * DD + DD + t] - wfa;
    float wda = Wd[o * 2 * DD + t];
    float wdb = Wd[o * 2 * DD + DD + t] - wda;
    Wlds[t] = make_float4(wfa, wfb, wda, wdb);
  }
  __syncthreads();

  const float* sb = src + (size_t)b * bs;
  {
    int c0 = t << 2;
    float4 uf[3], vf[3], ud[3], vd[3];
#pragma unroll
    for (int r = 0; r < 3; ++r) {
      uf[r] = make_float4(0.f, 0.f, 0.f, 0.f);
      vf[r] = make_float4(0.f, 0.f, 0.f, 0.f);
      ud[r] = make_float4(0.f, 0.f, 0.f, 0.f);
      vd[r] = make_float4(0.f, 0.f, 0.f, 0.f);
    }
#pragma unroll 2
    for (int i = 0; i < DD; ++i) {
      const float* row = sb + (size_t)i * 3 * NN + c0;
      float4 s[3];
      s[0] = *(const float4*)(row);
      s[1] = *(const float4*)(row + 1024);
      s[2] = *(const float4*)(row + 2048);
      float4 w = Wlds[i];
#pragma unroll
      for (int r = 0; r < 3; ++r) {
        uf[r].x += w.x * s[r].x; uf[r].y += w.x * s[r].y;
        uf[r].z += w.x * s[r].z; uf[r].w += w.x * s[r].w;
        vf[r].x += w.y * s[r].x; vf[r].y += w.y * s[r].y;
        vf[r].z += w.y * s[r].z; vf[r].w += w.y * s[r].w;
        ud[r].x += w.z * s[r].x; ud[r].y += w.z * s[r].y;
        ud[r].z += w.z * s[r].z; ud[r].w += w.z * s[r].w;
        vd[r].x += w.w * s[r].x; vd[r].y += w.w * s[r].y;
        vd[r].z += w.w * s[r].z; vd[r].w += w.w * s[r].w;
      }
    }
#pragma unroll
    for (int r = 0; r < 3; ++r) {
      int g = t + 256 * r;
      *(float4*)&Ulds[(g << 2) + 0] =
          make_float4(uf[r].x, ud[r].x, uf[r].y, ud[r].y);
      *(float4*)&Ulds[(g << 2) + 2] =
          make_float4(uf[r].z, ud[r].z, uf[r].w, ud[r].w);
      *(float4*)&Vlds[(g << 2) + 0] =
          make_float4(vf[r].x, vd[r].x, vf[r].y, vd[r].y);
      *(float4*)&Vlds[(g << 2) + 2] =
          make_float4(vf[r].z, vd[r].z, vf[r].w, vd[r].w);
    }
  }
  __syncthreads();

  const float inv_k = 1.f / KK;
  int cnt = NN / nsplit;
  int nbase = blockIdx.y * cnt;
  for (int n = nbase + t; n < nbase + cnt; n += 256) {
    float2 v0 = Vlds[n];
    float2 v1 = Vlds[NN + n];
    float2 v2 = Vlds[2 * NN + n];
    const int4* ip = (const int4*)(idx + (b * NN + n) * KK);
    float a0 = 0.f, a1 = 0.f, a2 = 0.f;
#pragma unroll
    for (int qq = 0; qq < 5; ++qq) {
      int4 iv = ip[qq];
      int nbs[4] = {iv.x, iv.y, iv.z, iv.w};
#pragma unroll
      for (int jj = 0; jj < 4; ++jj) {
        int nb = nbs[jj];
        float2 u0 = Ulds[nb];
        float2 u1 = Ulds[NN + nb];
        float2 u2 = Ulds[2 * NN + nb];
        float pf0 = u0.x + v0.x, pd0 = u0.y + v0.y;
        float pf1 = u1.x + v1.x, pd1 = u1.y + v1.y;
        float pf2 = u2.x + v2.x, pd2 = u2.y + v2.y;
        float dot = pf0 * pd0 + pf1 * pd1 + pf2 * pd2;
        float dsq = pd0 * pd0 + pd1 * pd1 + pd2 * pd2;
        float g = (dot >= 0.f) ? 0.f : 0.8f * dot / (dsq + 1e-6f);
        a0 += pf0 - g * pd0;
        a1 += pf1 - g * pd1;
        a2 += pf2 - g * pd2;
      }
    }
    size_t ob = (size_t)b * CCAT * 3 * NN + (size_t)(ooff + o) * 3 * NN + n;
    xcat[ob] = a0 * inv_k;
    xcat[ob + NN] = a1 * inv_k;
    xcat[ob + 2 * NN] = a2 * inv_k;
  }
}

// ---------------- prep: transpose Wf4 -> Wt[176][384] (zero-padded), zero pad
__global__ __launch_bounds__(256) void prep_kernel(
    const float* __restrict__ Wf4, float* __restrict__ Wt,
    float* __restrict__ zpad) {
  int o = blockIdx.x * 256 + threadIdx.x;  // 0..511
  int f = blockIdx.y;                      // 0..175
  if (o < WTLD)
    Wt[(size_t)f * WTLD + o] = (f < CCAT && o < 341) ? Wf4[o * CCAT + f] : 0.f;
  if (blockIdx.x == 0 && blockIdx.y == 0) zpad[threadIdx.x] = 0.f;
}

// ---------------- fused final GEMM + dvec + VN-leakyrelu + partial n-sum ----
// Async-DMA staging (global_load_lds w16): staged data never touches VGPRs.
// Double-buffered LDS, one barrier per tile. ~70-79 µs — structural limit
// for this structure (barrier vmcnt drain); declared done.
__device__ __forceinline__ void gl2lds16(const float* g, float* l) {
  __builtin_amdgcn_global_load_lds(
      (const __attribute__((address_space(1))) unsigned int*)g,
      (__attribute__((address_space(3))) unsigned int*)l, 16, 0, 0);
}

__global__ __launch_bounds__(256) void final_fused_kernel(
    const float* __restrict__ xcat, const float* __restrict__ Wt,
    const float* __restrict__ Wd4, const float* __restrict__ zpad,
    float* __restrict__ part) {
  __shared__ float Ws[2][16][64];     // [buf][f][o_col]   8.2 KB
  __shared__ float Xs[2][3][16][64];  // [buf][c][f][n]   24.6 KB
  __shared__ float Wda[176];
  int b = blockIdx.z;
  int o0 = blockIdx.y * 64;
  int n0 = blockIdx.x * 64;
  int t = threadIdx.x;
  int tx = t & 15, ty = t >> 4;

  if (t < 176) Wda[t] = (t < CCAT) ? Wd4[t] : 0.f;

  float acc[3][4][4];  // [c][o_i][n_j]
  float dv[3][4];      // [c][n_j]
#pragma unroll
  for (int c = 0; c < 3; ++c) {
#pragma unroll
    for (int i = 0; i < 4; ++i)
#pragma unroll
      for (int j = 0; j < 4; ++j) acc[c][i][j] = 0.f;
#pragma unroll
    for (int j = 0; j < 4; ++j) dv[c][j] = 0.f;
  }

  const float* xb = xcat + (size_t)b * CCAT * 3 * NN;
  const int NTILE = 11;  // 176 = 11*16 padded K

  {
    const float* wsrc = Wt + (size_t)ty * WTLD + o0 + (tx << 2);
    gl2lds16(wsrc, &Ws[0][ty][tx << 2]);
#pragma unroll
    for (int c = 0; c < 3; ++c) {
      const float* xsrc = xb + ((size_t)ty * 3 + c) * NN + n0 + (tx << 2);
      gl2lds16(xsrc, &Xs[0][c][ty][tx << 2]);
    }
  }

#pragma unroll 1
  for (int tt = 0; tt < NTILE; ++tt) {
    int buf = tt & 1;
    __syncthreads();  // vmcnt(0)+barrier: tile tt landed; buf^1 consumers done
    if (tt + 1 < NTILE) {
      int f = (tt + 1) * 16 + ty;
      const float* wsrc = Wt + (size_t)f * WTLD + o0 + (tx << 2);
      gl2lds16(wsrc, &Ws[buf ^ 1][ty][tx << 2]);
#pragma unroll
      for (int c = 0; c < 3; ++c) {
        const float* xsrc = (f < CCAT)
                                ? xb + ((size_t)f * 3 + c) * NN + n0 + (tx << 2)
                                : zpad + (tx << 2);
        gl2lds16(xsrc, &Xs[buf ^ 1][c][ty][tx << 2]);
      }
    }
#pragma unroll
    for (int f2 = 0; f2 < 16; ++f2) {
      float4 w = *(const float4*)&Ws[buf][f2][ty << 2];
      float wa[4] = {w.x, w.y, w.z, w.w};
      float wd = Wda[tt * 16 + f2];
#pragma unroll
      for (int c = 0; c < 3; ++c) {
        float4 x = *(const float4*)&Xs[buf][c][f2][tx << 2];
        float xa[4] = {x.x, x.y, x.z, x.w};
#pragma unroll
        for (int j = 0; j < 4; ++j) dv[c][j] += wd * xa[j];
#pragma unroll
        for (int i = 0; i < 4; ++i)
#pragma unroll
          for (int j = 0; j < 4; ++j) acc[c][i][j] += wa[i] * xa[j];
      }
    }
  }

  float s[3][4];
#pragma unroll
  for (int c = 0; c < 3; ++c)
#pragma unroll
    for (int i = 0; i < 4; ++i) s[c][i] = 0.f;
#pragma unroll
  for (int i = 0; i < 4; ++i) {
#pragma unroll
    for (int j = 0; j < 4; ++j) {
      float d0 = dv[0][j], d1 = dv[1][j], d2 = dv[2][j];
      float p0 = acc[0][i][j], p1 = acc[1][i][j], p2 = acc[2][i][j];
      float dot = p0 * d0 + p1 * d1 + p2 * d2;
      float dsq = d0 * d0 + d1 * d1 + d2 * d2;
      float g = (dot >= 0.f) ? 0.f : 0.8f * dot / (dsq + 1e-6f);
      s[0][i] += p0 - g * d0;
      s[1][i] += p1 - g * d1;
      s[2][i] += p2 - g * d2;
    }
  }

#pragma unroll
  for (int off = 1; off < 16; off <<= 1) {
#pragma unroll
    for (int c = 0; c < 3; ++c)
#pragma unroll
      for (int i = 0; i < 4; ++i) s[c][i] += __shfl_xor(s[c][i], off, 64);
  }
  if (tx == 0) {
#pragma unroll
    for (int i = 0; i < 4; ++i) {
      int o = o0 + (ty << 2) + i;
      if (o < 341) {
#pragma unroll
        for (int c = 0; c < 3; ++c)
          part[(((size_t)b * 341 + o) * 3 + c) * NT + blockIdx.x] = s[c][i];
      }
    }
  }
}

__global__ void final_reduce_kernel(const float* __restrict__ part,
                                    float* __restrict__ out) {
  int t = blockIdx.x * 256 + threadIdx.x;
  if (t >= BB * 341 * 3) return;
  const float* p = part + (size_t)t * NT;
  float s = 0.f;
#pragma unroll
  for (int nt = 0; nt < NT; ++nt) s += p[nt];
  out[t] = s * (1.f / 1024.f);
}

extern "C" void kernel_launch(void* const* d_in, const int* in_sizes, int n_in,
                              void* d_out, int out_size, void* d_ws,
                              size_t ws_size, hipStream_t stream) {
  (void)in_sizes; (void)n_in; (void)out_size; (void)ws_size;
  const float* x = (const float*)d_in[0];
  const float* Wf[5] = {(const float*)d_in[1], (const float*)d_in[3],
                        (const float*)d_in[5], (const float*)d_in[7],
                        (const float*)d_in[9]};
  const float* Wd[5] = {(const float*)d_in[2], (const float*)d_in[4],
                        (const float*)d_in[6], (const float*)d_in[8],
                        (const float*)d_in[10]};

  float* ws = (float*)d_ws;
  float* dist = ws;
  float* part = ws;
  float* Wt = ws + 262144;
  float* zpad = Wt + 176 * WTLD;
  size_t off = (size_t)BB * NN * NN;
  int* idx = (int*)(ws + off);
  off += (size_t)BB * NN * KK;
  float* xcat = ws + off;

  struct LayerCfg { int D, Co, inoff, ooff, nsplit; };
  const LayerCfg L[4] = {
      {1, 21, 0, 0, 4},
      {21, 21, 0, 21, 4},
      {21, 42, 21, 42, 2},
      {42, 85, 42, 84, 1},
  };

  for (int l = 0; l < 4; ++l) {
    const float* src = (l == 0) ? x : (xcat + (size_t)L[l].inoff * 3 * NN);
    int bs = (l == 0) ? 3 * NN : CCAT * 3 * NN;
    int D = L[l].D, Co = L[l].Co;

    dim3 dg(8, 8, BB);
    if (D == 1)
      dist_tile_kernel<3><<<dg, 256, 0, stream>>>(src, bs, dist);
    else if (D == 21)
      dist_tile_kernel<63><<<dg, 256, 0, stream>>>(src, bs, dist);
    else
      dist_tile_kernel<126><<<dg, 256, 0, stream>>>(src, bs, dist);

    topk_kernel<<<(BB * NN) / 4, 256, 0, stream>>>(dist, idx);

    dim3 eg(BB * Co, L[l].nsplit);
    if (D == 1)
      edge_fused_kernel<1><<<eg, 256, 0, stream>>>(
          src, bs, Co, L[l].nsplit, Wf[l], Wd[l], idx, L[l].ooff, xcat);
    else if (D == 21)
      edge_fused_kernel<21><<<eg, 256, 0, stream>>>(
          src, bs, Co, L[l].nsplit, Wf[l], Wd[l], idx, L[l].ooff, xcat);
    else
      edge_fused_kernel<42><<<eg, 256, 0, stream>>>(
          src, bs, Co, L[l].nsplit, Wf[l], Wd[l], idx, L[l].ooff, xcat);
  }

  prep_kernel<<<dim3(2, 176), 256, 0, stream>>>(Wf[4], Wt, zpad);
  final_fused_kernel<<<dim3(NT, 6, BB), 256, 0, stream>>>(xcat, Wt, Wd[4],
                                                          zpad, part);
  final_reduce_kernel<<<(BB * 341 * 3 + 255) / 256, 256, 0, stream>>>(
      part, (float*)d_out);
}

// Round 14
// 387.277 us; speedup vs baseline: 1.2005x; 1.0198x over previous
//
#include <hip/hip_runtime.h>
#include <cstddef>

#define BB 8
#define NN 1024
#define KK 20
#define CCAT 169
#define NT 16   // n-tiles of 64 in final fused GEMM
#define WTLD 384  // padded row length of transposed Wf4

// ---------------- neg dist, full grid, F-templated, double-buffered ---------
// (layers 2-4; layer 1 uses the fused knn3 kernel below)
template <int F>
__global__ __launch_bounds__(256) void dist_tile_kernel(
    const float* __restrict__ src, int bs, float* __restrict__ dist) {
  __shared__ float As[2][8][128];
  __shared__ float Bs[2][8][128];
  int b = blockIdx.z;
  int n0 = blockIdx.y * 128;
  int m0 = blockIdx.x * 128;
  int t = threadIdx.x;
  int tx = t & 15, ty = t >> 4;
  const float* p = src + (size_t)b * bs;

  float acc[8][8];
  float xn[8], xm[8];
#pragma unroll
  for (int i = 0; i < 8; ++i) {
    xn[i] = 0.f;
    xm[i] = 0.f;
#pragma unroll
    for (int j = 0; j < 8; ++j) acc[i][j] = 0.f;
  }

  int fr = t >> 5;
  int cc = (t & 31) << 2;
  constexpr int T = (F + 7) / 8;

  float4 av = {0.f, 0.f, 0.f, 0.f}, bv = {0.f, 0.f, 0.f, 0.f};
  if (fr < F) {  // tile 0
    av = *(const float4*)(p + (size_t)fr * NN + n0 + cc);
    bv = *(const float4*)(p + (size_t)fr * NN + m0 + cc);
  }
  *(float4*)&As[0][fr][cc] = av;
  *(float4*)&Bs[0][fr][cc] = bv;

#pragma unroll 1
  for (int k = 0; k < T; ++k) {
    __syncthreads();  // tile k staged; buf^1 consumers (tile k-1) done
    if (k + 1 < T) {
      int f = (k + 1) * 8 + fr;
      av = make_float4(0.f, 0.f, 0.f, 0.f);
      bv = make_float4(0.f, 0.f, 0.f, 0.f);
      if (f < F) {
        av = *(const float4*)(p + (size_t)f * NN + n0 + cc);
        bv = *(const float4*)(p + (size_t)f * NN + m0 + cc);
      }
    }
    const float(*A)[128] = As[k & 1];
    const float(*B)[128] = Bs[k & 1];
#pragma unroll
    for (int f2 = 0; f2 < 8; ++f2) {
      float4 al = *(const float4*)&A[f2][ty << 2];
      float4 ah = *(const float4*)&A[f2][64 + (ty << 2)];
      float4 bl = *(const float4*)&B[f2][tx << 2];
      float4 bh = *(const float4*)&B[f2][64 + (tx << 2)];
      float a[8] = {al.x, al.y, al.z, al.w, ah.x, ah.y, ah.z, ah.w};
      float bb[8] = {bl.x, bl.y, bl.z, bl.w, bh.x, bh.y, bh.z, bh.w};
#pragma unroll
      for (int i = 0; i < 8; ++i) xn[i] += a[i] * a[i];
#pragma unroll
      for (int j = 0; j < 8; ++j) xm[j] += bb[j] * bb[j];
#pragma unroll
      for (int i = 0; i < 8; ++i)
#pragma unroll
        for (int j = 0; j < 8; ++j) acc[i][j] += a[i] * bb[j];
    }
    if (k + 1 < T) {
      *(float4*)&As[(k + 1) & 1][fr][cc] = av;  // vmcnt wait lands HERE
      *(float4*)&Bs[(k + 1) & 1][fr][cc] = bv;
    }
  }

#pragma unroll
  for (int i = 0; i < 8; ++i)
#pragma unroll
    for (int j = 0; j < 8; ++j) acc[i][j] = 2.f * acc[i][j] - xn[i] - xm[j];

#pragma unroll
  for (int i = 0; i < 8; ++i) {
    int n = n0 + ((i < 4) ? ((ty << 2) + i) : (64 + (ty << 2) + i - 4));
    float* dr = dist + (((size_t)b * NN + n) << 10);
    *(float4*)(dr + m0 + (tx << 2)) =
        make_float4(acc[i][0], acc[i][1], acc[i][2], acc[i][3]);
    *(float4*)(dr + m0 + 64 + (tx << 2)) =
        make_float4(acc[i][4], acc[i][5], acc[i][6], acc[i][7]);
  }
}

// ---------------- shared top-k core: sort 16 keys, LDS queue, tournament ----
// Keys: hi32 = order-preserving float->uint map, lo32 = (1023-m): ties break
// toward LOWER index (jax semantics); all keys unique.
__device__ __forceinline__ void topk_core(
    unsigned long long key[16], unsigned long long (*q)[64], int lane,
    int* out) {
  // bitonic sort, descending (compile-time indices -> stays in VGPRs)
#pragma unroll
  for (int size = 2; size <= 16; size <<= 1) {
#pragma unroll
    for (int stride = size >> 1; stride > 0; stride >>= 1) {
#pragma unroll
      for (int i = 0; i < 16; ++i) {
        int j = i ^ stride;
        if (j > i) {
          unsigned long long a = key[i], c = key[j];
          bool desc = ((i & size) == 0);
          bool sw = desc ? (a < c) : (a > c);
          key[i] = sw ? c : a;
          key[j] = sw ? a : c;
        }
      }
    }
  }

  // spill sorted tail (slots 1..15) + sentinel; head stays in register
#pragma unroll
  for (int s = 1; s < 16; ++s) q[s - 1][lane] = key[s];
  q[15][lane] = 0ull;  // sentinel: below every real key, can't tie

  unsigned long long head = key[0];
  int ptr = 0;
  for (int r = 0; r < KK; ++r) {
    unsigned hv = (unsigned)(head >> 32);
    unsigned v = hv;
#pragma unroll
    for (int off = 32; off > 0; off >>= 1) {
      unsigned o = __shfl_xor(v, off, 64);
      v = (o > v) ? o : v;
    }
    unsigned long long tie = __ballot(hv == v);
    unsigned il;
    if (tie & (tie - 1)) {  // >=2 lanes tie in value: reduce low word
      unsigned c = (hv == v) ? (unsigned)head : 0u;
#pragma unroll
      for (int off = 32; off > 0; off >>= 1) {
        unsigned o = __shfl_xor(c, off, 64);
        c = (o > c) ? o : c;
      }
      il = c;
    } else {
      int wl = __builtin_ctzll(tie);
      il = __shfl((unsigned)head, wl, 64);
    }
    if (lane == 0) out[r] = (NN - 1) - (int)il;
    if (hv == v && (unsigned)head == il) {  // unique winner pops from LDS
      head = q[ptr][lane];
      ++ptr;
    }
  }
}

__device__ __forceinline__ unsigned long long mk_key(float val, int m) {
  unsigned u = __float_as_uint(val);
  u = (u & 0x80000000u) ? ~u : (u | 0x80000000u);
  return ((unsigned long long)u << 32) | (unsigned)(NN - 1 - m);
}

// ---------------- top-k from the dist matrix (layers 2-4) ----------------
__global__ __launch_bounds__(256) void topk_kernel(
    const float* __restrict__ dist, int* __restrict__ idx_out) {
  __shared__ unsigned long long q[4][16][64];  // 32 KB
  int wave = threadIdx.x >> 6;
  int lane = threadIdx.x & 63;
  int row = blockIdx.x * 4 + wave;
  const float* d = dist + ((size_t)row << 10);

  unsigned long long key[16];
  {
    const float4* dp = (const float4*)(d + (lane << 4));
#pragma unroll
    for (int qd = 0; qd < 4; ++qd) {
      float4 v4 = dp[qd];
      float vv[4] = {v4.x, v4.y, v4.z, v4.w};
#pragma unroll
      for (int e = 0; e < 4; ++e)
        key[(qd << 2) + e] = mk_key(vv[e], (lane << 4) + (qd << 2) + e);
    }
  }
  topk_core(key, q[wave], lane, idx_out + row * KK);
}

// ---------------- fused dist+topk for layer 1 (F=3): x fits in LDS ---------
// No 33.5 MB dist round-trip, one launch instead of two. Per-lane ownership
// strided (m = lane + s*64): conflict-free b32 LDS reads. Key encodes m
// explicitly -> selection identical regardless of ownership layout.
__global__ __launch_bounds__(256) void knn3_kernel(
    const float* __restrict__ src, int* __restrict__ idx_out) {
  __shared__ float xl[3 * NN];                 // 12 KB
  __shared__ unsigned long long q[4][16][64];  // 32 KB
  int b = blockIdx.y;
  int t = threadIdx.x;
  int wave = t >> 6;
  int lane = t & 63;
  int n = blockIdx.x * 4 + wave;  // row within batch
  const float* sb = src + (size_t)b * 3 * NN;

#pragma unroll
  for (int r = 0; r < 3; ++r)
    ((float4*)xl)[t + 256 * r] = ((const float4*)sb)[t + 256 * r];
  __syncthreads();

  float xn0 = xl[n], xn1 = xl[NN + n], xn2 = xl[2 * NN + n];
  float xnn = xn0 * xn0 + xn1 * xn1 + xn2 * xn2;

  unsigned long long key[16];
#pragma unroll
  for (int s = 0; s < 16; ++s) {
    int m = lane + (s << 6);
    float xm0 = xl[m], xm1 = xl[NN + m], xm2 = xl[2 * NN + m];
    float dot = xn0 * xm0 + xn1 * xm1 + xn2 * xm2;
    float xmn = xm0 * xm0 + xm1 * xm1 + xm2 * xm2;
    key[s] = mk_key(2.f * dot - xnn - xmn, m);
  }
  topk_core(key, q[wave], lane, idx_out + ((size_t)b * NN + n) * KK);
}

// ---------------- fused transform + edge combine + mean over k --------------
// Packed LDS: UA[n]={uf0,ud0,uf1,ud1}, UB[n]={uf2,ud2} (same for V) ->
// 2 LDS reads per gather instead of 3. Values & expression order identical
// to the float2x3 layout -> bitwise-identical xcat.
template <int DD>
__global__ __launch_bounds__(256) void edge_fused_kernel(
    const float* __restrict__ src, int bs, int Co, int nsplit,
    const float* __restrict__ Wf, const float* __restrict__ Wd,
    const int* __restrict__ idx, int ooff, float* __restrict__ xcat) {
  __shared__ float4 UA[NN];   // 16 KB
  __shared__ float2 UB2[NN];  // 8 KB
  __shared__ float4 VA[NN];   // 16 KB
  __shared__ float2 VB2[NN];  // 8 KB
  __shared__ float4 Wlds[48];
  int bo = blockIdx.x;
  int b = bo / Co, o = bo % Co;
  int t = threadIdx.x;

  if (t < DD) {
    float wfa = Wf[o * 2 * DD + t];
    float wfb = Wf[o * 2 * DD + DD + t] - wfa;
    float wda = Wd[o * 2 * DD + t];
    float wdb = Wd[o * 2 * DD + DD + t] - wda;
    Wlds[t] = make_float4(wfa, wfb, wda, wdb);
  }
  __syncthreads();

  const float* sb = src + (size_t)b * bs;
  {
    int c0 = t << 2;
    float uf[3][4], vf[3][4], ud[3][4], vd[3][4];
#pragma unroll
    for (int r = 0; r < 3; ++r)
#pragma unroll
      for (int e = 0; e < 4; ++e) {
        uf[r][e] = 0.f; vf[r][e] = 0.f; ud[r][e] = 0.f; vd[r][e] = 0.f;
      }
#pragma unroll 2
    for (int i = 0; i < DD; ++i) {
      const float* row = sb + (size_t)i * 3 * NN + c0;
      float4 s0 = *(const float4*)(row);
      float4 s1 = *(const float4*)(row + 1024);
      float4 s2 = *(const float4*)(row + 2048);
      float se[3][4] = {{s0.x, s0.y, s0.z, s0.w},
                        {s1.x, s1.y, s1.z, s1.w},
                        {s2.x, s2.y, s2.z, s2.w}};
      float4 w = Wlds[i];
#pragma unroll
      for (int r = 0; r < 3; ++r)
#pragma unroll
        for (int e = 0; e < 4; ++e) {
          uf[r][e] += w.x * se[r][e];
          vf[r][e] += w.y * se[r][e];
          ud[r][e] += w.z * se[r][e];
          vd[r][e] += w.w * se[r][e];
        }
    }
#pragma unroll
    for (int e = 0; e < 4; ++e) {
      int n = (t << 2) + e;
      UA[n] = make_float4(uf[0][e], ud[0][e], uf[1][e], ud[1][e]);
      UB2[n] = make_float2(uf[2][e], ud[2][e]);
      VA[n] = make_float4(vf[0][e], vd[0][e], vf[1][e], vd[1][e]);
      VB2[n] = make_float2(vf[2][e], vd[2][e]);
    }
  }
  __syncthreads();

  const float inv_k = 1.f / KK;
  int cnt = NN / nsplit;
  int nbase = blockIdx.y * cnt;
  for (int n = nbase + t; n < nbase + cnt; n += 256) {
    float4 va = VA[n];
    float2 vb = VB2[n];
    const int4* ip = (const int4*)(idx + (b * NN + n) * KK);
    float a0 = 0.f, a1 = 0.f, a2 = 0.f;
#pragma unroll
    for (int qq = 0; qq < 5; ++qq) {
      int4 iv = ip[qq];
      int nbs[4] = {iv.x, iv.y, iv.z, iv.w};
#pragma unroll
      for (int jj = 0; jj < 4; ++jj) {
        int nb = nbs[jj];
        float4 ua = UA[nb];
        float2 ub = UB2[nb];
        float pf0 = ua.x + va.x, pd0 = ua.y + va.y;
        float pf1 = ua.z + va.z, pd1 = ua.w + va.w;
        float pf2 = ub.x + vb.x, pd2 = ub.y + vb.y;
        float dot = pf0 * pd0 + pf1 * pd1 + pf2 * pd2;
        float dsq = pd0 * pd0 + pd1 * pd1 + pd2 * pd2;
        float g = (dot >= 0.f) ? 0.f : 0.8f * dot / (dsq + 1e-6f);
        a0 += pf0 - g * pd0;
        a1 += pf1 - g * pd1;
        a2 += pf2 - g * pd2;
      }
    }
    size_t ob = (size_t)b * CCAT * 3 * NN + (size_t)(ooff + o) * 3 * NN + n;
    xcat[ob] = a0 * inv_k;
    xcat[ob + NN] = a1 * inv_k;
    xcat[ob + 2 * NN] = a2 * inv_k;
  }
}

// ---------------- prep: transpose Wf4 -> Wt[176][384] (zero-padded), zero pad
__global__ __launch_bounds__(256) void prep_kernel(
    const float* __restrict__ Wf4, float* __restrict__ Wt,
    float* __restrict__ zpad) {
  int o = blockIdx.x * 256 + threadIdx.x;  // 0..511
  int f = blockIdx.y;                      // 0..175
  if (o < WTLD)
    Wt[(size_t)f * WTLD + o] = (f < CCAT && o < 341) ? Wf4[o * CCAT + f] : 0.f;
  if (blockIdx.x == 0 && blockIdx.y == 0) zpad[threadIdx.x] = 0.f;
}

// ---------------- fused final GEMM + dvec + VN-leakyrelu + partial n-sum ----
// Async-DMA staging (global_load_lds w16). Declared done at ~68-79 µs.
__device__ __forceinline__ void gl2lds16(const float* g, float* l) {
  __builtin_amdgcn_global_load_lds(
      (const __attribute__((address_space(1))) unsigned int*)g,
      (__attribute__((address_space(3))) unsigned int*)l, 16, 0, 0);
}

__global__ __launch_bounds__(256) void final_fused_kernel(
    const float* __restrict__ xcat, const float* __restrict__ Wt,
    const float* __restrict__ Wd4, const float* __restrict__ zpad,
    float* __restrict__ part) {
  __shared__ float Ws[2][16][64];     // [buf][f][o_col]   8.2 KB
  __shared__ float Xs[2][3][16][64];  // [buf][c][f][n]   24.6 KB
  __shared__ float Wda[176];
  int b = blockIdx.z;
  int o0 = blockIdx.y * 64;
  int n0 = blockIdx.x * 64;
  int t = threadIdx.x;
  int tx = t & 15, ty = t >> 4;

  if (t < 176) Wda[t] = (t < CCAT) ? Wd4[t] : 0.f;

  float acc[3][4][4];  // [c][o_i][n_j]
  float dv[3][4];      // [c][n_j]
#pragma unroll
  for (int c = 0; c < 3; ++c) {
#pragma unroll
    for (int i = 0; i < 4; ++i)
#pragma unroll
      for (int j = 0; j < 4; ++j) acc[c][i][j] = 0.f;
#pragma unroll
    for (int j = 0; j < 4; ++j) dv[c][j] = 0.f;
  }

  const float* xb = xcat + (size_t)b * CCAT * 3 * NN;
  const int NTILE = 11;  // 176 = 11*16 padded K

  {
    const float* wsrc = Wt + (size_t)ty * WTLD + o0 + (tx << 2);
    gl2lds16(wsrc, &Ws[0][ty][tx << 2]);
#pragma unroll
    for (int c = 0; c < 3; ++c) {
      const float* xsrc = xb + ((size_t)ty * 3 + c) * NN + n0 + (tx << 2);
      gl2lds16(xsrc, &Xs[0][c][ty][tx << 2]);
    }
  }

#pragma unroll 1
  for (int tt = 0; tt < NTILE; ++tt) {
    int buf = tt & 1;
    __syncthreads();  // vmcnt(0)+barrier: tile tt landed; buf^1 consumers done
    if (tt + 1 < NTILE) {
      int f = (tt + 1) * 16 + ty;
      const float* wsrc = Wt + (size_t)f * WTLD + o0 + (tx << 2);
      gl2lds16(wsrc, &Ws[buf ^ 1][ty][tx << 2]);
#pragma unroll
      for (int c = 0; c < 3; ++c) {
        const float* xsrc = (f < CCAT)
                                ? xb + ((size_t)f * 3 + c) * NN + n0 + (tx << 2)
                                : zpad + (tx << 2);
        gl2lds16(xsrc, &Xs[buf ^ 1][c][ty][tx << 2]);
      }
    }
#pragma unroll
    for (int f2 = 0; f2 < 16; ++f2) {
      float4 w = *(const float4*)&Ws[buf][f2][ty << 2];
      float wa[4] = {w.x, w.y, w.z, w.w};
      float wd = Wda[tt * 16 + f2];
#pragma unroll
      for (int c = 0; c < 3; ++c) {
        float4 x = *(const float4*)&Xs[buf][c][f2][tx << 2];
        float xa[4] = {x.x, x.y, x.z, x.w};
#pragma unroll
        for (int j = 0; j < 4; ++j) dv[c][j] += wd * xa[j];
#pragma unroll
        for (int i = 0; i < 4; ++i)
#pragma unroll
          for (int j = 0; j < 4; ++j) acc[c][i][j] += wa[i] * xa[j];
      }
    }
  }

  float s[3][4];
#pragma unroll
  for (int c = 0; c < 3; ++c)
#pragma unroll
    for (int i = 0; i < 4; ++i) s[c][i] = 0.f;
#pragma unroll
  for (int i = 0; i < 4; ++i) {
#pragma unroll
    for (int j = 0; j < 4; ++j) {
      float d0 = dv[0][j], d1 = dv[1][j], d2 = dv[2][j];
      float p0 = acc[0][i][j], p1 = acc[1][i][j], p2 = acc[2][i][j];
      float dot = p0 * d0 + p1 * d1 + p2 * d2;
      float dsq = d0 * d0 + d1 * d1 + d2 * d2;
      float g = (dot >= 0.f) ? 0.f : 0.8f * dot / (dsq + 1e-6f);
      s[0][i] += p0 - g * d0;
      s[1][i] += p1 - g * d1;
      s[2][i] += p2 - g * d2;
    }
  }

#pragma unroll
  for (int off = 1; off < 16; off <<= 1) {
#pragma unroll
    for (int c = 0; c < 3; ++c)
#pragma unroll
      for (int i = 0; i < 4; ++i) s[c][i] += __shfl_xor(s[c][i], off, 64);
  }
  if (tx == 0) {
#pragma unroll
    for (int i = 0; i < 4; ++i) {
      int o = o0 + (ty << 2) + i;
      if (o < 341) {
#pragma unroll
        for (int c = 0; c < 3; ++c)
          part[(((size_t)b * 341 + o) * 3 + c) * NT + blockIdx.x] = s[c][i];
      }
    }
  }
}

__global__ void final_reduce_kernel(const float* __restrict__ part,
                                    float* __restrict__ out) {
  int t = blockIdx.x * 256 + threadIdx.x;
  if (t >= BB * 341 * 3) return;
  const float* p = part + (size_t)t * NT;
  float s = 0.f;
#pragma unroll
  for (int nt = 0; nt < NT; ++nt) s += p[nt];
  out[t] = s * (1.f / 1024.f);
}

extern "C" void kernel_launch(void* const* d_in, const int* in_sizes, int n_in,
                              void* d_out, int out_size, void* d_ws,
                              size_t ws_size, hipStream_t stream) {
  (void)in_sizes; (void)n_in; (void)out_size; (void)ws_size;
  const float* x = (const float*)d_in[0];
  const float* Wf[5] = {(const float*)d_in[1], (const float*)d_in[3],
                        (const float*)d_in[5], (const float*)d_in[7],
                        (const float*)d_in[9]};
  const float* Wd[5] = {(const float*)d_in[2], (const float*)d_in[4],
                        (const float*)d_in[6], (const float*)d_in[8],
                        (const float*)d_in[10]};

  float* ws = (float*)d_ws;
  float* dist = ws;
  float* part = ws;
  float* Wt = ws + 262144;
  float* zpad = Wt + 176 * WTLD;
  size_t off = (size_t)BB * NN * NN;
  int* idx = (int*)(ws + off);
  off += (size_t)BB * NN * KK;
  float* xcat = ws + off;

  struct LayerCfg { int D, Co, inoff, ooff, nsplit; };
  const LayerCfg L[4] = {
      {1, 21, 0, 0, 4},
      {21, 21, 0, 21, 4},
      {21, 42, 21, 42, 2},
      {42, 85, 42, 84, 1},
  };

  for (int l = 0; l < 4; ++l) {
    const float* src = (l == 0) ? x : (xcat + (size_t)L[l].inoff * 3 * NN);
    int bs = (l == 0) ? 3 * NN : CCAT * 3 * NN;
    int D = L[l].D, Co = L[l].Co;

    if (l == 0) {
      knn3_kernel<<<dim3(NN / 4, BB), 256, 0, stream>>>(x, idx);
    } else {
      dim3 dg(8, 8, BB);
      if (D == 21)
        dist_tile_kernel<63><<<dg, 256, 0, stream>>>(src, bs, dist);
      else
        dist_tile_kernel<126><<<dg, 256, 0, stream>>>(src, bs, dist);
      topk_kernel<<<(BB * NN) / 4, 256, 0, stream>>>(dist, idx);
    }

    dim3 eg(BB * Co, L[l].nsplit);
    if (D == 1)
      edge_fused_kernel<1><<<eg, 256, 0, stream>>>(
          src, bs, Co, L[l].nsplit, Wf[l], Wd[l], idx, L[l].ooff, xcat);
    else if (D == 21)
      edge_fused_kernel<21><<<eg, 256, 0, stream>>>(
          src, bs, Co, L[l].nsplit, Wf[l], Wd[l], idx, L[l].ooff, xcat);
    else
      edge_fused_kernel<42><<<eg, 256, 0, stream>>>(
          src, bs, Co, L[l].nsplit, Wf[l], Wd[l], idx, L[l].ooff, xcat);
  }

  prep_kernel<<<dim3(2, 176), 256, 0, stream>>>(Wf[4], Wt, zpad);
  final_fused_kernel<<<dim3(NT, 6, BB), 256, 0, stream>>>(xcat, Wt, Wd[4],
                                                          zpad, part);
  final_reduce_kernel<<<(BB * 341 * 3 + 255) / 256, 256, 0, stream>>>(
      part, (float*)d_out);
}